// Round 1
// baseline (200.511 us; speedup 1.0000x reference)
//
#include <hip/hip_runtime.h>

// ---------------------------------------------------------------------------
// MS Deformable Attention (Deformable-DETR), MI355X gfx950.
// Pipeline:
//   1. value  = input_flatten @ W_val^T  + b_val   [45012 x 512]  (bf16 MFMA)
//   2. off    = query @ W_off^T  + b_off           [4000 x 256]   (bf16 MFMA)
//   3. logits = query @ W_attn^T + b_attn          [4000 x 128]   (bf16 MFMA)
//   4. msout  = bilinear-sample(value, loc, softmax(logits))  [4000 x 512] f32
//   5. out    = msout @ W_out^T + b_out            [4000 x 256]   (bf16 MFMA)
// ---------------------------------------------------------------------------

typedef __attribute__((ext_vector_type(4))) float f32x4;
typedef __attribute__((ext_vector_type(8))) short bf16x8;

static __device__ __forceinline__ short f2bf(float f) {
    unsigned u = __builtin_bit_cast(unsigned, f);
    u += 0x7FFFu + ((u >> 16) & 1u);   // round-to-nearest-even
    return (short)(u >> 16);
}

static __device__ __forceinline__ bf16x8 cvt16lo(const f32x4& a, const f32x4& b) {
    bf16x8 r;
    r[0] = f2bf(a[0]); r[1] = f2bf(a[1]); r[2] = f2bf(a[2]); r[3] = f2bf(a[3]);
    r[4] = f2bf(b[0]); r[5] = f2bf(b[1]); r[6] = f2bf(b[2]); r[7] = f2bf(b[3]);
    return r;
}

// C[M,N] = A[M,K] @ B[N,K]^T + bias[N]; f32 global, bf16 MFMA f32-accum.
// BM=BN=128, BK=32. grid=(ceil(M/128), N/128), block=256 (4 waves, 2x2).
// N, K must be multiples of 128 / 32 respectively (true for all our calls).
__global__ __launch_bounds__(256)
void gemm_bf16_tn(const float* __restrict__ A, const float* __restrict__ B,
                  const float* __restrict__ bias, float* __restrict__ C,
                  int M, int N, int K) {
    // +8 pad (stride 40 shorts = 80B) to break power-of-2 LDS bank stride
    __shared__ short As[128][40];
    __shared__ short Bs[128][40];

    const int bm = blockIdx.x, bn = blockIdx.y;
    const int tid  = threadIdx.x;
    const int lane = tid & 63;
    const int wid  = tid >> 6;
    const int wm   = wid >> 1, wn = wid & 1;

    // staging map: thread pair covers one 32-f32 row slice
    const int srow = tid >> 1;
    const int scol = (tid & 1) << 4;   // 0 or 16

    int arow = bm * 128 + srow; if (arow > M - 1) arow = M - 1;   // clamp tail reads
    const float* pa = A + (size_t)arow * K + scol;
    const float* pb = B + (size_t)(bn * 128 + srow) * K + scol;

    f32x4 acc[4][4] = {};

    const int k8 = (lane >> 4) << 3;   // 0,8,16,24 : K offset of this lane's frag
    const int fr = lane & 15;

    for (int k0 = 0; k0 < K; k0 += 32) {
        f32x4 a0 = ((const f32x4*)(pa + k0))[0];
        f32x4 a1 = ((const f32x4*)(pa + k0))[1];
        f32x4 a2 = ((const f32x4*)(pa + k0))[2];
        f32x4 a3 = ((const f32x4*)(pa + k0))[3];
        f32x4 b0 = ((const f32x4*)(pb + k0))[0];
        f32x4 b1 = ((const f32x4*)(pb + k0))[1];
        f32x4 b2 = ((const f32x4*)(pb + k0))[2];
        f32x4 b3 = ((const f32x4*)(pb + k0))[3];

        __syncthreads();   // previous iteration's frag reads must be done
        *(bf16x8*)&As[srow][scol]     = cvt16lo(a0, a1);
        *(bf16x8*)&As[srow][scol + 8] = cvt16lo(a2, a3);
        *(bf16x8*)&Bs[srow][scol]     = cvt16lo(b0, b1);
        *(bf16x8*)&Bs[srow][scol + 8] = cvt16lo(b2, b3);
        __syncthreads();

        bf16x8 af[4], bf[4];
#pragma unroll
        for (int m = 0; m < 4; m++)
            af[m] = *(const bf16x8*)&As[wm * 64 + m * 16 + fr][k8];
#pragma unroll
        for (int nn = 0; nn < 4; nn++)
            bf[nn] = *(const bf16x8*)&Bs[wn * 64 + nn * 16 + fr][k8];
#pragma unroll
        for (int m = 0; m < 4; m++)
#pragma unroll
            for (int nn = 0; nn < 4; nn++)
                acc[m][nn] = __builtin_amdgcn_mfma_f32_16x16x32_bf16(
                    af[m], bf[nn], acc[m][nn], 0, 0, 0);
    }

    // C/D layout (m89-verified): col = lane&15, row = (lane>>4)*4 + j
    const int fq = lane >> 4;
    const int crow0 = bm * 128 + wm * 64 + fq * 4;
    const int ccol0 = bn * 128 + wn * 64 + fr;
#pragma unroll
    for (int m = 0; m < 4; m++) {
#pragma unroll
        for (int nn = 0; nn < 4; nn++) {
            const int col = ccol0 + nn * 16;
            const float bv = bias[col];
#pragma unroll
            for (int j = 0; j < 4; j++) {
                const int row = crow0 + m * 16 + j;
                if (row < M) C[(size_t)row * N + col] = acc[m][nn][j] + bv;
            }
        }
    }
}

// ---------------------------------------------------------------------------
// Sampling: one wave per (n, q, h). lane = channel d (0..63).
// All per-point math is wave-uniform; gathers are 64x4B = 256B coalesced.
// ---------------------------------------------------------------------------
__global__ __launch_bounds__(256)
void sample_k(const float* __restrict__ value,    // [4][11253][512]
              const float* __restrict__ refp,     // [4][1000][4][2]
              const float* __restrict__ off,      // [4][1000][256]  (h,l,p,2)
              const float* __restrict__ logits,   // [4][1000][128]  (h,l*p)
              float* __restrict__ msout)          // [4][1000][512]
{
    const int id   = blockIdx.x * 4 + (threadIdx.x >> 6);   // 0..31999
    const int lane = threadIdx.x & 63;
    const int n = id / 8000;
    const int r = id - n * 8000;
    const int q = r >> 3;
    const int h = r & 7;
    const size_t nq = (size_t)n * 1000 + q;

    // softmax over 16 points of this head (computed redundantly per lane)
    const float* lg = logits + nq * 128 + h * 16;
    float e[16];
    float mx = lg[0];
#pragma unroll
    for (int p = 1; p < 16; p++) mx = fmaxf(mx, lg[p]);
    float s = 0.f;
#pragma unroll
    for (int p = 0; p < 16; p++) { e[p] = __expf(lg[p] - mx); s += e[p]; }
    const float inv = 1.f / s;

    const float* rp = refp + nq * 8;
    const float* op = off + nq * 256 + h * 32;

    const int   HS [4] = {92, 46, 23, 12};
    const int   ST4[4] = {0, 8464, 10580, 11109};

    float acc = 0.f;
#pragma unroll
    for (int lv = 0; lv < 4; lv++) {
        const int W = HS[lv], Hh = HS[lv], st = ST4[lv];
        const float rx = rp[lv * 2 + 0], ry = rp[lv * 2 + 1];
        const float* vb = value + ((size_t)n * 11253 + st) * 512 + h * 64 + lane;
#pragma unroll
        for (int p = 0; p < 4; p++) {
            const float ox = op[lv * 8 + p * 2 + 0];
            const float oy = op[lv * 8 + p * 2 + 1];
            const float a  = e[lv * 4 + p] * inv;
            // loc = ref + off/(w,h); x = loc.x*w - 0.5 = ref.x*w + off.x - 0.5
            const float x = rx * (float)W + ox - 0.5f;
            const float y = ry * (float)Hh + oy - 0.5f;
            const float xf = floorf(x), yf = floorf(y);
            const int x0 = (int)xf, y0 = (int)yf;
            const float lx = x - xf, ly = y - yf;
            const float w00 = (1.f - lx) * (1.f - ly);
            const float w01 = lx * (1.f - ly);
            const float w10 = (1.f - lx) * ly;
            const float w11 = lx * ly;
            if (y0 >= 0 && y0 < Hh) {
                if (x0 >= 0 && x0 < W)
                    acc += a * w00 * vb[(size_t)(y0 * W + x0) * 512];
                if (x0 + 1 >= 0 && x0 + 1 < W)
                    acc += a * w01 * vb[(size_t)(y0 * W + x0 + 1) * 512];
            }
            if (y0 + 1 >= 0 && y0 + 1 < Hh) {
                if (x0 >= 0 && x0 < W)
                    acc += a * w10 * vb[(size_t)((y0 + 1) * W + x0) * 512];
                if (x0 + 1 >= 0 && x0 + 1 < W)
                    acc += a * w11 * vb[(size_t)((y0 + 1) * W + x0 + 1) * 512];
            }
        }
    }
    msout[nq * 512 + h * 64 + lane] = acc;
}

// ---------------------------------------------------------------------------
extern "C" void kernel_launch(void* const* d_in, const int* in_sizes, int n_in,
                              void* d_out, int out_size, void* d_ws, size_t ws_size,
                              hipStream_t stream) {
    (void)in_sizes; (void)n_in; (void)out_size; (void)ws_size;

    const float* query  = (const float*)d_in[0];
    const float* refp   = (const float*)d_in[1];
    const float* inpf   = (const float*)d_in[2];
    // d_in[3], d_in[4]: spatial shapes / level starts — compile-time constants
    const float* W_off  = (const float*)d_in[5];
    const float* b_off  = (const float*)d_in[6];
    const float* W_attn = (const float*)d_in[7];
    const float* b_attn = (const float*)d_in[8];
    const float* W_val  = (const float*)d_in[9];
    const float* b_val  = (const float*)d_in[10];
    const float* W_out  = (const float*)d_in[11];
    const float* b_out  = (const float*)d_in[12];
    float* out = (float*)d_out;

    char* ws = (char*)d_ws;
    float* value  = (float*)(ws);                         // 45012*512*4 = 92,184,576
    float* offb   = (float*)(ws + 92184576);              // 4000*256*4  =  4,096,000
    float* logits = (float*)(ws + 92184576 + 4096000);    // 4000*128*4  =  2,048,000
    float* msout  = (float*)(ws + 92184576 + 4096000 + 2048000);  // 4000*512*4 = 8,192,000

    // 1. value projection: M=45012, N=512, K=256
    gemm_bf16_tn<<<dim3(352, 4), 256, 0, stream>>>(inpf, W_val, b_val, value, 45012, 512, 256);
    // 2. offsets: M=4000, N=256, K=256
    gemm_bf16_tn<<<dim3(32, 2), 256, 0, stream>>>(query, W_off, b_off, offb, 4000, 256, 256);
    // 3. attention logits: M=4000, N=128, K=256
    gemm_bf16_tn<<<dim3(32, 1), 256, 0, stream>>>(query, W_attn, b_attn, logits, 4000, 128, 256);
    // 4. sampling (fused softmax): 32000 waves, 4 per block
    sample_k<<<8000, 256, 0, stream>>>(value, refp, offb, logits, msout);
    // 5. output projection: M=4000, N=256, K=512
    gemm_bf16_tn<<<dim3(32, 2), 256, 0, stream>>>(msout, W_out, b_out, out, 4000, 256, 512);
}

// Round 2
// 154.373 us; speedup vs baseline: 1.2989x; 1.2989x over previous
//
#include <hip/hip_runtime.h>

// ---------------------------------------------------------------------------
// MS Deformable Attention (Deformable-DETR), MI355X gfx950.
//   1. valueT = bf16( input_flatten @ W_val^T + b_val )  laid out [n][h][pix][64]
//   2. off    = query @ W_off^T  + b_off   [4000 x 256] f32
//   3. logits = query @ W_attn^T + b_attn  [4000 x 128] f32
//   4. msout  = bilinear-sample(valueT, loc, softmax(logits)) [4000 x 512] f32
//      - paired-corner gathers: one dword load covers both x-corners (bf16)
//   5. out    = msout @ W_out^T + b_out    [4000 x 256] f32
// ---------------------------------------------------------------------------

typedef __attribute__((ext_vector_type(4))) float f32x4;
typedef __attribute__((ext_vector_type(8))) short bf16x8;

static __device__ __forceinline__ short f2bf(float f) {
    unsigned u = __builtin_bit_cast(unsigned, f);
    u += 0x7FFFu + ((u >> 16) & 1u);   // round-to-nearest-even
    return (short)(u >> 16);
}

static __device__ __forceinline__ bf16x8 cvt16lo(const f32x4& a, const f32x4& b) {
    bf16x8 r;
    r[0] = f2bf(a[0]); r[1] = f2bf(a[1]); r[2] = f2bf(a[2]); r[3] = f2bf(a[3]);
    r[4] = f2bf(b[0]); r[5] = f2bf(b[1]); r[6] = f2bf(b[2]); r[7] = f2bf(b[3]);
    return r;
}

// C = A[M,K] @ B[N,K]^T + bias[N].  MODE 0: f32 row-major out.
// MODE 1: bf16 out, transposed to valueT[n][h][pix][64] (M = n*11253+pix, col = h*64+d).
template<int MODE>
__global__ __launch_bounds__(256)
void gemm_bf16_tn(const float* __restrict__ A, const float* __restrict__ B,
                  const float* __restrict__ bias, void* __restrict__ Cv,
                  int M, int N, int K) {
    __shared__ short As[128][40];
    __shared__ short Bs[128][40];

    const int bm = blockIdx.x, bn = blockIdx.y;
    const int tid  = threadIdx.x;
    const int lane = tid & 63;
    const int wid  = tid >> 6;
    const int wm   = wid >> 1, wn = wid & 1;

    const int srow = tid >> 1;
    const int scol = (tid & 1) << 4;

    int arow = bm * 128 + srow; if (arow > M - 1) arow = M - 1;
    const float* pa = A + (size_t)arow * K + scol;
    const float* pb = B + (size_t)(bn * 128 + srow) * K + scol;

    f32x4 acc[4][4] = {};

    const int k8 = (lane >> 4) << 3;
    const int fr = lane & 15;

    for (int k0 = 0; k0 < K; k0 += 32) {
        f32x4 a0 = ((const f32x4*)(pa + k0))[0];
        f32x4 a1 = ((const f32x4*)(pa + k0))[1];
        f32x4 a2 = ((const f32x4*)(pa + k0))[2];
        f32x4 a3 = ((const f32x4*)(pa + k0))[3];
        f32x4 b0 = ((const f32x4*)(pb + k0))[0];
        f32x4 b1 = ((const f32x4*)(pb + k0))[1];
        f32x4 b2 = ((const f32x4*)(pb + k0))[2];
        f32x4 b3 = ((const f32x4*)(pb + k0))[3];

        __syncthreads();
        *(bf16x8*)&As[srow][scol]     = cvt16lo(a0, a1);
        *(bf16x8*)&As[srow][scol + 8] = cvt16lo(a2, a3);
        *(bf16x8*)&Bs[srow][scol]     = cvt16lo(b0, b1);
        *(bf16x8*)&Bs[srow][scol + 8] = cvt16lo(b2, b3);
        __syncthreads();

        bf16x8 af[4], bfr[4];
#pragma unroll
        for (int m = 0; m < 4; m++)
            af[m] = *(const bf16x8*)&As[wm * 64 + m * 16 + fr][k8];
#pragma unroll
        for (int nn = 0; nn < 4; nn++)
            bfr[nn] = *(const bf16x8*)&Bs[wn * 64 + nn * 16 + fr][k8];
#pragma unroll
        for (int m = 0; m < 4; m++)
#pragma unroll
            for (int nn = 0; nn < 4; nn++)
                acc[m][nn] = __builtin_amdgcn_mfma_f32_16x16x32_bf16(
                    af[m], bfr[nn], acc[m][nn], 0, 0, 0);
    }

    const int fq = lane >> 4;
    const int crow0 = bm * 128 + wm * 64 + fq * 4;
    const int ccol0 = bn * 128 + wn * 64 + fr;
#pragma unroll
    for (int m = 0; m < 4; m++) {
#pragma unroll
        for (int nn = 0; nn < 4; nn++) {
            const int col = ccol0 + nn * 16;
            const float bv = bias[col];
#pragma unroll
            for (int j = 0; j < 4; j++) {
                const int row = crow0 + m * 16 + j;
                if (row < M) {
                    const float v = acc[m][nn][j] + bv;
                    if (MODE == 0) {
                        ((float*)Cv)[(size_t)row * N + col] = v;
                    } else {
                        const int n   = row / 11253;
                        const int pix = row - n * 11253;
                        const int h   = col >> 6;
                        const int d   = col & 63;
                        ((unsigned short*)Cv)[(((size_t)n * 8 + h) * 11253 + pix) * 64 + d]
                            = (unsigned short)f2bf(v);
                    }
                }
            }
        }
    }
}

// ---------------------------------------------------------------------------
// Sampling: one wave per (n, q, h). Lane l: channel pair (2*(l&31), +1) of
// x-corner (l>>5). One dword gather covers both x-corners of a bilinear row.
// ---------------------------------------------------------------------------
__global__ __launch_bounds__(256)
void sample_k(const unsigned short* __restrict__ valueT, // [4][8][11253][64] bf16
              const float* __restrict__ refp,            // [4][1000][4][2]
              const float* __restrict__ off,             // [4][1000][256]
              const float* __restrict__ logits,          // [4][1000][128]
              float* __restrict__ msout)                 // [4][1000][512]
{
    const int id   = __builtin_amdgcn_readfirstlane(blockIdx.x * 4 + (threadIdx.x >> 6));
    const int lane = threadIdx.x & 63;
    const int g    = lane >> 5;          // x-corner group (0: xb, 1: xb+1)
    const int c2   = (lane & 31) * 2;    // channel pair base

    const int n = id / 8000;
    const int r = id - n * 8000;
    const int q = r >> 3;
    const int h = r & 7;
    const int nq = n * 1000 + q;

    // softmax over the 16 points of this head (scalar loads, redundant per lane)
    const float* lg = logits + (size_t)nq * 128 + h * 16;
    float e[16];
    float mx = lg[0];
#pragma unroll
    for (int p = 1; p < 16; p++) mx = fmaxf(mx, lg[p]);
    float s = 0.f;
#pragma unroll
    for (int p = 0; p < 16; p++) { e[p] = __expf(lg[p] - mx); s += e[p]; }
    const float inv = 1.f / s;

    const float* rp = refp + (size_t)nq * 8;
    const float* op = off + (size_t)nq * 256 + h * 32;
    const unsigned int* vb =
        (const unsigned int*)(valueT + ((size_t)n * 8 + h) * 11253 * 64);

    const int HS [4] = {92, 46, 23, 12};
    const int ST4[4] = {0, 8464, 10580, 11109};

    float acc0 = 0.f, acc1 = 0.f;
#pragma unroll
    for (int lv = 0; lv < 4; lv++) {
        const int W = HS[lv], Hh = HS[lv], st = ST4[lv];
        const float rx = rp[lv * 2 + 0], ry = rp[lv * 2 + 1];
#pragma unroll
        for (int p = 0; p < 4; p++) {
            const float a  = e[lv * 4 + p] * inv;
            const float ox = op[lv * 8 + p * 2 + 0];
            const float oy = op[lv * 8 + p * 2 + 1];
            const float x = rx * (float)W  + ox - 0.5f;
            const float y = ry * (float)Hh + oy - 0.5f;
            const float xf = floorf(x), yf = floorf(y);
            const int x0 = (int)xf, y0 = (int)yf;
            const float lx = x - xf, ly = y - yf;

            // paired-corner x weight for this lane's group
            const int xb = min(max(x0, 0), W - 2);
            const int xg = xb + g;
            float wx = 0.f;
            if (xg == x0     && (unsigned)x0       < (unsigned)W) wx = 1.f - lx;
            if (xg == x0 + 1 && (unsigned)(x0 + 1) < (unsigned)W) wx = lx;

            const float wy0 = ((unsigned)y0       < (unsigned)Hh) ? a * (1.f - ly) : 0.f;
            const float wy1 = ((unsigned)(y0 + 1) < (unsigned)Hh) ? a * ly         : 0.f;
            const int yc0 = min(max(y0, 0), Hh - 1);
            const int yc1 = min(max(y0 + 1, 0), Hh - 1);

            // 32 dwords per pixel; load covers pixels (xb, xb+1)
            const unsigned int d0 = vb[(size_t)(st + yc0 * W + xb) * 32 + lane];
            const unsigned int d1 = vb[(size_t)(st + yc1 * W + xb) * 32 + lane];

            const float w0 = wx * wy0, w1 = wx * wy1;
            const float f00 = __builtin_bit_cast(float, d0 << 16);
            const float f01 = __builtin_bit_cast(float, d0 & 0xffff0000u);
            const float f10 = __builtin_bit_cast(float, d1 << 16);
            const float f11 = __builtin_bit_cast(float, d1 & 0xffff0000u);
            acc0 = fmaf(w0, f00, acc0);
            acc1 = fmaf(w0, f01, acc1);
            acc0 = fmaf(w1, f10, acc0);
            acc1 = fmaf(w1, f11, acc1);
        }
    }

    // combine the two x-corner halves: lane l + lane l^32 hold same channels
    const float o0 = acc0 + __shfl(acc0, lane ^ 32);
    const float o1 = acc1 + __shfl(acc1, lane ^ 32);
    if (lane < 32) {
        float2 v2 = make_float2(o0, o1);
        *(float2*)&msout[(size_t)nq * 512 + h * 64 + c2] = v2;
    }
}

// ---------------------------------------------------------------------------
extern "C" void kernel_launch(void* const* d_in, const int* in_sizes, int n_in,
                              void* d_out, int out_size, void* d_ws, size_t ws_size,
                              hipStream_t stream) {
    (void)in_sizes; (void)n_in; (void)out_size; (void)ws_size;

    const float* query  = (const float*)d_in[0];
    const float* refp   = (const float*)d_in[1];
    const float* inpf   = (const float*)d_in[2];
    const float* W_off  = (const float*)d_in[5];
    const float* b_off  = (const float*)d_in[6];
    const float* W_attn = (const float*)d_in[7];
    const float* b_attn = (const float*)d_in[8];
    const float* W_val  = (const float*)d_in[9];
    const float* b_val  = (const float*)d_in[10];
    const float* W_out  = (const float*)d_in[11];
    const float* b_out  = (const float*)d_in[12];
    float* out = (float*)d_out;

    char* ws = (char*)d_ws;
    unsigned short* valueT = (unsigned short*)(ws);            // 45012*512*2 = 46,092,288
    float* offb   = (float*)(ws + 46092288);                   // 4000*256*4  =  4,096,000
    float* logits = (float*)(ws + 46092288 + 4096000);         // 4000*128*4  =  2,048,000
    float* msout  = (float*)(ws + 46092288 + 4096000 + 2048000); // 4000*512*4 = 8,192,000

    // 1. value projection -> bf16 transposed [n][h][pix][64]
    gemm_bf16_tn<1><<<dim3(352, 4), 256, 0, stream>>>(inpf, W_val, b_val, valueT, 45012, 512, 256);
    // 2. offsets
    gemm_bf16_tn<0><<<dim3(32, 2), 256, 0, stream>>>(query, W_off, b_off, offb, 4000, 256, 256);
    // 3. attention logits
    gemm_bf16_tn<0><<<dim3(32, 1), 256, 0, stream>>>(query, W_attn, b_attn, logits, 4000, 128, 256);
    // 4. sampling (fused softmax)
    sample_k<<<8000, 256, 0, stream>>>(valueT, refp, offb, logits, msout);
    // 5. output projection
    gemm_bf16_tn<0><<<dim3(32, 2), 256, 0, stream>>>(msout, W_out, b_out, out, 4000, 256, 512);
}

// Round 4
// 139.468 us; speedup vs baseline: 1.4377x; 1.1069x over previous
//
#include <hip/hip_runtime.h>

// ---------------------------------------------------------------------------
// MS Deformable Attention (Deformable-DETR), MI355X gfx950.
//   0. cvt    : all f32 operands -> bf16 (one streaming kernel)
//   1. valueT = bf16( input_flatten @ W_val^T + b_val ) -> [n][h][pix][64]
//   2. off    = query @ W_off^T  + b_off   [4000 x 256] f32
//   3. logits = query @ W_attn^T + b_attn  [4000 x 128] f32
//   4. msout  = bilinear-sample(valueT, loc, softmax(logits)) -> bf16
//   5. out    = msout @ W_out^T + b_out    [4000 x 256] f32
// GEMM = R1-proven geometry (register staging, padded LDS); only the staging
// input dtype changed f32->bf16 (conversion hoisted to cvt_k).
// ---------------------------------------------------------------------------

typedef __attribute__((ext_vector_type(4))) float f32x4;
typedef __attribute__((ext_vector_type(8))) short bf16x8;

static __device__ __forceinline__ unsigned short f2bf(float f) {
    unsigned u = __builtin_bit_cast(unsigned, f);
    u += 0x7FFFu + ((u >> 16) & 1u);   // round-to-nearest-even
    return (unsigned short)(u >> 16);
}

// ---------------------------------------------------------------------------
// f32 -> bf16 conversion of all operands into one packed buffer.
// Element offsets (all segments divisible by 8 -> no thread straddles):
//   inpf 0 | query 11523072 | W_off 12547072 | W_attn 12612608
//   | W_val 12645376 | W_out 12776448 | total 12907520
// ---------------------------------------------------------------------------
__global__ __launch_bounds__(256)
void cvt_k(const float* __restrict__ s0, const float* __restrict__ s1,
           const float* __restrict__ s2, const float* __restrict__ s3,
           const float* __restrict__ s4, const float* __restrict__ s5,
           unsigned short* __restrict__ dst) {
    const size_t i8 = ((size_t)blockIdx.x * 256 + threadIdx.x) * 8;
    if (i8 >= 12907520u) return;
    const float* sp; size_t loc;
    if (i8 < 11523072u)      { sp = s0; loc = i8; }
    else if (i8 < 12547072u) { sp = s1; loc = i8 - 11523072u; }
    else if (i8 < 12612608u) { sp = s2; loc = i8 - 12547072u; }
    else if (i8 < 12645376u) { sp = s3; loc = i8 - 12612608u; }
    else if (i8 < 12776448u) { sp = s4; loc = i8 - 12645376u; }
    else                     { sp = s5; loc = i8 - 12776448u; }
    f32x4 a = *(const f32x4*)(sp + loc);
    f32x4 b = *(const f32x4*)(sp + loc + 4);
    bf16x8 r;
    r[0] = f2bf(a[0]); r[1] = f2bf(a[1]); r[2] = f2bf(a[2]); r[3] = f2bf(a[3]);
    r[4] = f2bf(b[0]); r[5] = f2bf(b[1]); r[6] = f2bf(b[2]); r[7] = f2bf(b[3]);
    *(bf16x8*)(dst + i8) = r;
}

// ---------------------------------------------------------------------------
// bf16 GEMM: C = A[M,K] @ B[N,K]^T + bias[N]. BM=BN=128, BK=32, 4 waves 2x2.
// MODE 0: C f32 row-major [M,N].
// MODE 1: C bf16 scattered to valueT[n][h][pix][64]; row=pixel, col=h*64+d.
// ---------------------------------------------------------------------------
template<int MODE>
__global__ __launch_bounds__(256)
void gemm_bf16_tn(const unsigned short* __restrict__ A,
                  const unsigned short* __restrict__ B,
                  const float* __restrict__ bias, void* __restrict__ Cv,
                  int M, int N, int K) {
    __shared__ unsigned short As[128][40];
    __shared__ unsigned short Bs[128][40];

    const int bm = blockIdx.x, bn = blockIdx.y;
    const int tid  = threadIdx.x;
    const int lane = tid & 63;
    const int wid  = tid >> 6;
    const int wm   = wid >> 1, wn = wid & 1;

    const int srow = tid >> 1;
    const int scol = (tid & 1) << 4;   // 0 or 16

    int arow = bm * 128 + srow; if (arow > M - 1) arow = M - 1;   // tail clamp
    const unsigned short* pa = A + (size_t)arow * K + scol;
    const unsigned short* pb = B + (size_t)(bn * 128 + srow) * K + scol;

    f32x4 acc[4][4] = {};
    const int k8 = (lane >> 4) << 3;
    const int fr = lane & 15;

    for (int k0 = 0; k0 < K; k0 += 32) {
        bf16x8 a0 = *(const bf16x8*)(pa + k0);
        bf16x8 a1 = *(const bf16x8*)(pa + k0 + 8);
        bf16x8 b0 = *(const bf16x8*)(pb + k0);
        bf16x8 b1 = *(const bf16x8*)(pb + k0 + 8);

        __syncthreads();   // previous iteration's frag reads done
        *(bf16x8*)&As[srow][scol]     = a0;
        *(bf16x8*)&As[srow][scol + 8] = a1;
        *(bf16x8*)&Bs[srow][scol]     = b0;
        *(bf16x8*)&Bs[srow][scol + 8] = b1;
        __syncthreads();

        bf16x8 af[4], bfr[4];
#pragma unroll
        for (int m = 0; m < 4; m++)
            af[m] = *(const bf16x8*)&As[wm * 64 + m * 16 + fr][k8];
#pragma unroll
        for (int nn = 0; nn < 4; nn++)
            bfr[nn] = *(const bf16x8*)&Bs[wn * 64 + nn * 16 + fr][k8];
#pragma unroll
        for (int m = 0; m < 4; m++)
#pragma unroll
            for (int nn = 0; nn < 4; nn++)
                acc[m][nn] = __builtin_amdgcn_mfma_f32_16x16x32_bf16(
                    af[m], bfr[nn], acc[m][nn], 0, 0, 0);
    }

    // C/D layout (m89-verified): col = lane&15, row = (lane>>4)*4 + j
    const int fq = lane >> 4;
    const int crow0 = bm * 128 + wm * 64 + fq * 4;
    const int ccol0 = bn * 128 + wn * 64 + fr;
#pragma unroll
    for (int m = 0; m < 4; m++) {
#pragma unroll
        for (int nn = 0; nn < 4; nn++) {
            const int col = ccol0 + nn * 16;
            const float bv = bias[col];
#pragma unroll
            for (int j = 0; j < 4; j++) {
                const int row = crow0 + m * 16 + j;
                if (row < M) {
                    const float v = acc[m][nn][j] + bv;
                    if (MODE == 0) {
                        ((float*)Cv)[(size_t)row * N + col] = v;
                    } else {
                        const int n   = row / 11253;
                        const int pix = row - n * 11253;
                        const int h   = col >> 6;
                        const int d   = col & 63;
                        ((unsigned short*)Cv)[(((size_t)n * 8 + h) * 11253 + pix) * 64 + d]
                            = f2bf(v);
                    }
                }
            }
        }
    }
}

// ---------------------------------------------------------------------------
// Sampling (R1-proven): one wave per (n, q, h). Lane l: channel pair
// (2*(l&31), +1) of x-corner (l>>5). One dword gather covers both x-corners.
// Output msout packed bf16.
// ---------------------------------------------------------------------------
__global__ __launch_bounds__(256)
void sample_k(const unsigned short* __restrict__ valueT, // [4][8][11253][64] bf16
              const float* __restrict__ refp,            // [4][1000][4][2]
              const float* __restrict__ off,             // [4][1000][256]
              const float* __restrict__ logits,          // [4][1000][128]
              unsigned int* __restrict__ msout)          // [4][1000][256] dwords
{
    const int id   = __builtin_amdgcn_readfirstlane(blockIdx.x * 4 + (threadIdx.x >> 6));
    const int lane = threadIdx.x & 63;
    const int g    = lane >> 5;          // x-corner group (0: xb, 1: xb+1)

    const int n = id / 8000;
    const int r = id - n * 8000;
    const int q = r >> 3;
    const int h = r & 7;
    const int nq = n * 1000 + q;

    // softmax over the 16 points of this head (scalar loads, redundant per lane)
    const float* lg = logits + (size_t)nq * 128 + h * 16;
    float e[16];
    float mx = lg[0];
#pragma unroll
    for (int p = 1; p < 16; p++) mx = fmaxf(mx, lg[p]);
    float s = 0.f;
#pragma unroll
    for (int p = 0; p < 16; p++) { e[p] = __expf(lg[p] - mx); s += e[p]; }
    const float inv = 1.f / s;

    const float* rp = refp + (size_t)nq * 8;
    const float* op = off + (size_t)nq * 256 + h * 32;
    const unsigned int* vb =
        (const unsigned int*)(valueT + ((size_t)n * 8 + h) * 11253 * 64);

    const int HS [4] = {92, 46, 23, 12};
    const int ST4[4] = {0, 8464, 10580, 11109};

    float acc0 = 0.f, acc1 = 0.f;
#pragma unroll
    for (int lv = 0; lv < 4; lv++) {
        const int W = HS[lv], Hh = HS[lv], st = ST4[lv];
        const float rx = rp[lv * 2 + 0], ry = rp[lv * 2 + 1];
#pragma unroll
        for (int p = 0; p < 4; p++) {
            const float a  = e[lv * 4 + p] * inv;
            const float ox = op[lv * 8 + p * 2 + 0];
            const float oy = op[lv * 8 + p * 2 + 1];
            const float x = rx * (float)W  + ox - 0.5f;
            const float y = ry * (float)Hh + oy - 0.5f;
            const float xf = floorf(x), yf = floorf(y);
            const int x0 = (int)xf, y0 = (int)yf;
            const float lx = x - xf, ly = y - yf;

            const int xb = min(max(x0, 0), W - 2);
            const int xg = xb + g;
            float wx = 0.f;
            if (xg == x0     && (unsigned)x0       < (unsigned)W) wx = 1.f - lx;
            if (xg == x0 + 1 && (unsigned)(x0 + 1) < (unsigned)W) wx = lx;

            const float wy0 = ((unsigned)y0       < (unsigned)Hh) ? a * (1.f - ly) : 0.f;
            const float wy1 = ((unsigned)(y0 + 1) < (unsigned)Hh) ? a * ly         : 0.f;
            const int yc0 = min(max(y0, 0), Hh - 1);
            const int yc1 = min(max(y0 + 1, 0), Hh - 1);

            const unsigned int d0 = vb[(size_t)(st + yc0 * W + xb) * 32 + lane];
            const unsigned int d1 = vb[(size_t)(st + yc1 * W + xb) * 32 + lane];

            const float w0 = wx * wy0, w1 = wx * wy1;
            const float f00 = __builtin_bit_cast(float, d0 << 16);
            const float f01 = __builtin_bit_cast(float, d0 & 0xffff0000u);
            const float f10 = __builtin_bit_cast(float, d1 << 16);
            const float f11 = __builtin_bit_cast(float, d1 & 0xffff0000u);
            acc0 = fmaf(w0, f00, acc0);
            acc1 = fmaf(w0, f01, acc1);
            acc0 = fmaf(w1, f10, acc0);
            acc1 = fmaf(w1, f11, acc1);
        }
    }

    const float o0 = acc0 + __shfl(acc0, lane ^ 32);
    const float o1 = acc1 + __shfl(acc1, lane ^ 32);
    if (lane < 32) {
        const unsigned u = (unsigned)f2bf(o0) | ((unsigned)f2bf(o1) << 16);
        msout[(size_t)nq * 256 + h * 32 + (lane & 31)] = u;
    }
}

// ---------------------------------------------------------------------------
extern "C" void kernel_launch(void* const* d_in, const int* in_sizes, int n_in,
                              void* d_out, int out_size, void* d_ws, size_t ws_size,
                              hipStream_t stream) {
    (void)in_sizes; (void)n_in; (void)out_size; (void)ws_size;

    const float* query  = (const float*)d_in[0];
    const float* refp   = (const float*)d_in[1];
    const float* inpf   = (const float*)d_in[2];
    const float* W_off  = (const float*)d_in[5];
    const float* b_off  = (const float*)d_in[6];
    const float* W_attn = (const float*)d_in[7];
    const float* b_attn = (const float*)d_in[8];
    const float* W_val  = (const float*)d_in[9];
    const float* b_val  = (const float*)d_in[10];
    const float* W_out  = (const float*)d_in[11];
    const float* b_out  = (const float*)d_in[12];
    float* out = (float*)d_out;

    char* ws = (char*)d_ws;
    unsigned short* bf = (unsigned short*)ws;                    // 25,815,040 B
    unsigned short* inpfb   = bf;
    unsigned short* queryb  = bf + 11523072;
    unsigned short* W_offb  = bf + 12547072;
    unsigned short* W_attnb = bf + 12612608;
    unsigned short* W_valb  = bf + 12645376;
    unsigned short* W_outb  = bf + 12776448;
    unsigned short* valueT  = (unsigned short*)(ws + 25815040);  // 46,092,288 B
    float* offb   = (float*)(ws + 71907328);                     //  4,096,000 B
    float* logits = (float*)(ws + 76003328);                     //  2,048,000 B
    unsigned int* msoutu = (unsigned int*)(ws + 78051328);       //  4,096,000 B
    unsigned short* msoutb = (unsigned short*)msoutu;

    // 0. convert everything to bf16
    cvt_k<<<6303, 256, 0, stream>>>(inpf, query, W_off, W_attn, W_val, W_out, bf);
    // 1. value projection -> bf16 transposed [n][h][pix][64]
    gemm_bf16_tn<1><<<dim3(352, 4), 256, 0, stream>>>(inpfb, W_valb, b_val, valueT, 45012, 512, 256);
    // 2. offsets
    gemm_bf16_tn<0><<<dim3(32, 2), 256, 0, stream>>>(queryb, W_offb, b_off, offb, 4000, 256, 256);
    // 3. attention logits
    gemm_bf16_tn<0><<<dim3(32, 1), 256, 0, stream>>>(queryb, W_attnb, b_attn, logits, 4000, 128, 256);
    // 4. sampling (fused softmax), msout bf16
    sample_k<<<8000, 256, 0, stream>>>(valueT, refp, offb, logits, msoutu);
    // 5. output projection
    gemm_bf16_tn<0><<<dim3(32, 2), 256, 0, stream>>>(msoutb, W_outb, b_out, out, 4000, 256, 512);
}

// Round 6
// 122.445 us; speedup vs baseline: 1.6376x; 1.1390x over previous
//
#include <hip/hip_runtime.h>

// ---------------------------------------------------------------------------
// MS Deformable Attention (Deformable-DETR), MI355X gfx950.
//   0. cvt    : all f32 operands -> bf16 (one streaming kernel)
//   1. valueT = bf16( input_flatten @ W_val^T + b_val ) -> [n][h][pix][64]
//   2. off    = query @ W_off^T  + b_off   [4000 x 256] f32
//   3. logits = query @ W_attn^T + b_attn  [4000 x 128] f32
//   4. msout  = bilinear-sample(valueT, loc, softmax(logits)) -> bf16
//      (lane-parallel point metadata + shfl broadcast; single kernel)
//   5. out    = msout @ W_out^T + b_out    [4000 x 256] f32
// Everything except the inside of sample_k is verbatim from the passing R4.
// ---------------------------------------------------------------------------

typedef __attribute__((ext_vector_type(4))) float f32x4;
typedef __attribute__((ext_vector_type(8))) short bf16x8;

static __device__ __forceinline__ unsigned short f2bf(float f) {
    unsigned u = __builtin_bit_cast(unsigned, f);
    u += 0x7FFFu + ((u >> 16) & 1u);   // round-to-nearest-even
    return (unsigned short)(u >> 16);
}
static __device__ __forceinline__ float bflo(unsigned d) {
    return __builtin_bit_cast(float, d << 16);
}
static __device__ __forceinline__ float bfhi(unsigned d) {
    return __builtin_bit_cast(float, d & 0xffff0000u);
}

// ---------------------------------------------------------------------------
// f32 -> bf16 conversion of all operands into one packed buffer.
//   inpf 0 | query 11523072 | W_off 12547072 | W_attn 12612608
//   | W_val 12645376 | W_out 12776448 | total 12907520
// ---------------------------------------------------------------------------
__global__ __launch_bounds__(256)
void cvt_k(const float* __restrict__ s0, const float* __restrict__ s1,
           const float* __restrict__ s2, const float* __restrict__ s3,
           const float* __restrict__ s4, const float* __restrict__ s5,
           unsigned short* __restrict__ dst) {
    const size_t i8 = ((size_t)blockIdx.x * 256 + threadIdx.x) * 8;
    if (i8 >= 12907520u) return;
    const float* sp; size_t loc;
    if (i8 < 11523072u)      { sp = s0; loc = i8; }
    else if (i8 < 12547072u) { sp = s1; loc = i8 - 11523072u; }
    else if (i8 < 12612608u) { sp = s2; loc = i8 - 12547072u; }
    else if (i8 < 12645376u) { sp = s3; loc = i8 - 12612608u; }
    else if (i8 < 12776448u) { sp = s4; loc = i8 - 12645376u; }
    else                     { sp = s5; loc = i8 - 12776448u; }
    f32x4 a = *(const f32x4*)(sp + loc);
    f32x4 b = *(const f32x4*)(sp + loc + 4);
    bf16x8 r;
    r[0] = f2bf(a[0]); r[1] = f2bf(a[1]); r[2] = f2bf(a[2]); r[3] = f2bf(a[3]);
    r[4] = f2bf(b[0]); r[5] = f2bf(b[1]); r[6] = f2bf(b[2]); r[7] = f2bf(b[3]);
    *(bf16x8*)(dst + i8) = r;
}

// ---------------------------------------------------------------------------
// bf16 GEMM (R4-proven): C = A[M,K] @ B[N,K]^T + bias[N]. BM=BN=128, BK=32.
// MODE 0: C f32 row-major [M,N].
// MODE 1: C bf16 scattered to valueT[n][h][pix][64]; row=pixel, col=h*64+d.
// ---------------------------------------------------------------------------
template<int MODE>
__global__ __launch_bounds__(256)
void gemm_bf16_tn(const unsigned short* __restrict__ A,
                  const unsigned short* __restrict__ B,
                  const float* __restrict__ bias, void* __restrict__ Cv,
                  int M, int N, int K) {
    __shared__ unsigned short As[128][40];
    __shared__ unsigned short Bs[128][40];

    const int bm = blockIdx.x, bn = blockIdx.y;
    const int tid  = threadIdx.x;
    const int lane = tid & 63;
    const int wid  = tid >> 6;
    const int wm   = wid >> 1, wn = wid & 1;

    const int srow = tid >> 1;
    const int scol = (tid & 1) << 4;   // 0 or 16

    int arow = bm * 128 + srow; if (arow > M - 1) arow = M - 1;   // tail clamp
    const unsigned short* pa = A + (size_t)arow * K + scol;
    const unsigned short* pb = B + (size_t)(bn * 128 + srow) * K + scol;

    f32x4 acc[4][4] = {};
    const int k8 = (lane >> 4) << 3;
    const int fr = lane & 15;

    for (int k0 = 0; k0 < K; k0 += 32) {
        bf16x8 a0 = *(const bf16x8*)(pa + k0);
        bf16x8 a1 = *(const bf16x8*)(pa + k0 + 8);
        bf16x8 b0 = *(const bf16x8*)(pb + k0);
        bf16x8 b1 = *(const bf16x8*)(pb + k0 + 8);

        __syncthreads();   // previous iteration's frag reads done
        *(bf16x8*)&As[srow][scol]     = a0;
        *(bf16x8*)&As[srow][scol + 8] = a1;
        *(bf16x8*)&Bs[srow][scol]     = b0;
        *(bf16x8*)&Bs[srow][scol + 8] = b1;
        __syncthreads();

        bf16x8 af[4], bfr[4];
#pragma unroll
        for (int m = 0; m < 4; m++)
            af[m] = *(const bf16x8*)&As[wm * 64 + m * 16 + fr][k8];
#pragma unroll
        for (int nn = 0; nn < 4; nn++)
            bfr[nn] = *(const bf16x8*)&Bs[wn * 64 + nn * 16 + fr][k8];
#pragma unroll
        for (int m = 0; m < 4; m++)
#pragma unroll
            for (int nn = 0; nn < 4; nn++)
                acc[m][nn] = __builtin_amdgcn_mfma_f32_16x16x32_bf16(
                    af[m], bfr[nn], acc[m][nn], 0, 0, 0);
    }

    // C/D layout (m89-verified): col = lane&15, row = (lane>>4)*4 + j
    const int fq = lane >> 4;
    const int crow0 = bm * 128 + wm * 64 + fq * 4;
    const int ccol0 = bn * 128 + wn * 64 + fr;
#pragma unroll
    for (int m = 0; m < 4; m++) {
#pragma unroll
        for (int nn = 0; nn < 4; nn++) {
            const int col = ccol0 + nn * 16;
            const float bv = bias[col];
#pragma unroll
            for (int j = 0; j < 4; j++) {
                const int row = crow0 + m * 16 + j;
                if (row < M) {
                    const float v = acc[m][nn][j] + bv;
                    if (MODE == 0) {
                        ((float*)Cv)[(size_t)row * N + col] = v;
                    } else {
                        const int n   = row / 11253;
                        const int pix = row - n * 11253;
                        const int h   = col >> 6;
                        const int d   = col & 63;
                        ((unsigned short*)Cv)[(((size_t)n * 8 + h) * 11253 + pix) * 64 + d]
                            = f2bf(v);
                    }
                }
            }
        }
    }
}

// ---------------------------------------------------------------------------
// Sampling: one wave per (n, q, h). Softmax reduction is R4-verbatim scalar
// (uniform loads; no runtime-indexed array). Bilinear metadata computed
// lane-parallel: lane l handles point p=l&15; lanes 0-15 carry x-corner-0
// weights, lanes 16-31 x-corner-1. Gather loop broadcasts meta from lane
// p+16*g via __shfl; per point: 2 coalesced row-gathers + 4 FMA.
// ---------------------------------------------------------------------------
__global__ __launch_bounds__(256)
void sample_k(const unsigned short* __restrict__ valueT, // [4][8][11253][64] bf16
              const float* __restrict__ refp,            // [4][1000][4][2]
              const float* __restrict__ off,             // [4][1000][256]
              const float* __restrict__ logits,          // [4][1000][128]
              unsigned int* __restrict__ msout)          // [4][1000][256] dwords
{
    const int id   = __builtin_amdgcn_readfirstlane(blockIdx.x * 4 + (threadIdx.x >> 6));
    const int lane = threadIdx.x & 63;
    const int g    = lane >> 5;          // x-corner group (0: xb, 1: xb+1)

    const int n = id / 8000;
    const int r = id - n * 8000;
    const int q = r >> 3;
    const int h = r & 7;
    const int nq = n * 1000 + q;

    // softmax reduction over the 16 points (scalar, uniform loads — R4 form)
    const float* lgp = logits + (size_t)nq * 128 + h * 16;
    float mx = lgp[0];
#pragma unroll
    for (int pp = 1; pp < 16; pp++) mx = fmaxf(mx, lgp[pp]);
    float s = 0.f;
#pragma unroll
    for (int pp = 0; pp < 16; pp++) s += __expf(lgp[pp] - mx);

    // per-point metadata on lane groups of 16 (lanes 0-31 are the sources)
    const int p  = lane & 15;
    const int lv = p >> 2;
    const int W  = lv == 0 ? 92 : lv == 1 ? 46 : lv == 2 ? 23 : 12;  // H == W
    const int st = lv == 0 ? 0 : lv == 1 ? 8464 : lv == 2 ? 10580 : 11109;

    const float a  = __expf(lgp[p] - mx) / s;
    const float rx = refp[(size_t)nq * 8 + lv * 2 + 0];
    const float ry = refp[(size_t)nq * 8 + lv * 2 + 1];
    const float ox = off[(size_t)nq * 256 + h * 32 + p * 2 + 0];
    const float oy = off[(size_t)nq * 256 + h * 32 + p * 2 + 1];

    const float x = rx * (float)W + ox - 0.5f;
    const float y = ry * (float)W + oy - 0.5f;
    const float xf = floorf(x), yf = floorf(y);
    const int x0 = (int)xf, y0 = (int)yf;
    const float lx = x - xf, ly = y - yf;
    const int xb = min(max(x0, 0), W - 2);
    const int yb = min(max(y0, 0), W - 2);
    // weight of pixel xb+dx: ==x0 -> 1-lx, ==x0+1 -> lx, else 0 (same for y)
    const float wx0 = (xb     == x0) ? (1.f - lx) : ((xb     == x0 + 1) ? lx : 0.f);
    const float wx1 = (xb + 1 == x0) ? (1.f - lx) : ((xb + 1 == x0 + 1) ? lx : 0.f);
    const float wy0 = (yb     == y0) ? (1.f - ly) : ((yb     == y0 + 1) ? ly : 0.f);
    const float wy1 = (yb + 1 == y0) ? (1.f - ly) : ((yb + 1 == y0 + 1) ? ly : 0.f);
    const int idx0v = st + yb * W + xb;
    const int idx1v = idx0v + W;
    const float wxs = (lane & 16) ? wx1 : wx0;   // lane group picks its x-corner
    const float wav = a * wxs * wy0;
    const float wbv = a * wxs * wy1;

    const unsigned int* vb =
        (const unsigned int*)valueT + ((size_t)n * 8 + h) * 11253 * 32;

    float acc0 = 0.f, acc1 = 0.f;
    const int srcb = g << 4;
#pragma unroll
    for (int pp = 0; pp < 16; pp++) {
        const int src = pp + srcb;           // lane pp (g=0) or pp+16 (g=1)
        const int   i0 = __shfl(idx0v, src);
        const int   i1 = __shfl(idx1v, src);
        const float w0 = __shfl(wav,   src);
        const float w1 = __shfl(wbv,   src);
        const unsigned d0 = vb[i0 * 32 + lane];   // lane>=32 reads pixel+1
        const unsigned d1 = vb[i1 * 32 + lane];
        acc0 = fmaf(w0, bflo(d0), acc0);
        acc1 = fmaf(w0, bfhi(d0), acc1);
        acc0 = fmaf(w1, bflo(d1), acc0);
        acc1 = fmaf(w1, bfhi(d1), acc1);
    }

    acc0 += __shfl(acc0, lane ^ 32);
    acc1 += __shfl(acc1, lane ^ 32);
    if (lane < 32) {
        const unsigned u = (unsigned)f2bf(acc0) | ((unsigned)f2bf(acc1) << 16);
        msout[(size_t)nq * 256 + h * 32 + (lane & 31)] = u;
    }
}

// ---------------------------------------------------------------------------
extern "C" void kernel_launch(void* const* d_in, const int* in_sizes, int n_in,
                              void* d_out, int out_size, void* d_ws, size_t ws_size,
                              hipStream_t stream) {
    (void)in_sizes; (void)n_in; (void)out_size; (void)ws_size;

    const float* query  = (const float*)d_in[0];
    const float* refp   = (const float*)d_in[1];
    const float* inpf   = (const float*)d_in[2];
    const float* W_off  = (const float*)d_in[5];
    const float* b_off  = (const float*)d_in[6];
    const float* W_attn = (const float*)d_in[7];
    const float* b_attn = (const float*)d_in[8];
    const float* W_val  = (const float*)d_in[9];
    const float* b_val  = (const float*)d_in[10];
    const float* W_out  = (const float*)d_in[11];
    const float* b_out  = (const float*)d_in[12];
    float* out = (float*)d_out;

    char* ws = (char*)d_ws;
    unsigned short* bf = (unsigned short*)ws;                    // 25,815,040 B
    unsigned short* inpfb   = bf;
    unsigned short* queryb  = bf + 11523072;
    unsigned short* W_offb  = bf + 12547072;
    unsigned short* W_attnb = bf + 12612608;
    unsigned short* W_valb  = bf + 12645376;
    unsigned short* W_outb  = bf + 12776448;
    unsigned short* valueT  = (unsigned short*)(ws + 25815040);  // 46,092,288 B
    float* offb   = (float*)(ws + 71907328);                     //  4,096,000 B
    float* logits = (float*)(ws + 76003328);                     //  2,048,000 B
    unsigned int* msoutu = (unsigned int*)(ws + 78051328);       //  4,096,000 B
    unsigned short* msoutb = (unsigned short*)msoutu;

    // 0. convert everything to bf16
    cvt_k<<<6303, 256, 0, stream>>>(inpf, query, W_off, W_attn, W_val, W_out, bf);
    // 1. value projection -> bf16 transposed [n][h][pix][64]
    gemm_bf16_tn<1><<<dim3(352, 4), 256, 0, stream>>>(inpfb, W_valb, b_val, valueT, 45012, 512, 256);
    // 2. offsets
    gemm_bf16_tn<0><<<dim3(32, 2), 256, 0, stream>>>(queryb, W_offb, b_off, offb, 4000, 256, 256);
    // 3. attention logits
    gemm_bf16_tn<0><<<dim3(32, 1), 256, 0, stream>>>(queryb, W_attnb, b_attn, logits, 4000, 128, 256);
    // 4. sampling (fused softmax), msout bf16
    sample_k<<<8000, 256, 0, stream>>>(valueT, refp, offb, logits, msoutu);
    // 5. output projection
    gemm_bf16_tn<0><<<dim3(32, 2), 256, 0, stream>>>(msoutb, W_outb, b_out, out, 4000, 256, 512);
}

// Round 7
// 114.781 us; speedup vs baseline: 1.7469x; 1.0668x over previous
//
#include <hip/hip_runtime.h>

// ---------------------------------------------------------------------------
// MS Deformable Attention (Deformable-DETR), MI355X gfx950.
//   0. cvt    : all f32 operands -> bf16 (one streaming kernel)
//   1. valueT = bf16( input_flatten @ W_val^T + b_val ) -> [n][h][pix][64]
//      (MODE1 epilogue: per-wave LDS transpose -> coalesced 8B stores)
//   2. off    = query @ W_off^T  + b_off   [4000 x 256] f32
//   3. logits = query @ W_attn^T + b_attn  [4000 x 128] f32
//   4. msout  = bilinear-sample(valueT, loc, softmax(logits)) -> bf16
//   5. out    = msout @ W_out^T + b_out    [4000 x 256] f32
// Only the MODE1 epilogue changed vs the passing R6 kernel.
// ---------------------------------------------------------------------------

typedef __attribute__((ext_vector_type(4))) float f32x4;
typedef __attribute__((ext_vector_type(8))) short bf16x8;
typedef __attribute__((ext_vector_type(4))) short bf16x4;

static __device__ __forceinline__ unsigned short f2bf(float f) {
    unsigned u = __builtin_bit_cast(unsigned, f);
    u += 0x7FFFu + ((u >> 16) & 1u);   // round-to-nearest-even
    return (unsigned short)(u >> 16);
}
static __device__ __forceinline__ float bflo(unsigned d) {
    return __builtin_bit_cast(float, d << 16);
}
static __device__ __forceinline__ float bfhi(unsigned d) {
    return __builtin_bit_cast(float, d & 0xffff0000u);
}

// ---------------------------------------------------------------------------
// f32 -> bf16 conversion of all operands into one packed buffer.
//   inpf 0 | query 11523072 | W_off 12547072 | W_attn 12612608
//   | W_val 12645376 | W_out 12776448 | total 12907520
// ---------------------------------------------------------------------------
__global__ __launch_bounds__(256)
void cvt_k(const float* __restrict__ s0, const float* __restrict__ s1,
           const float* __restrict__ s2, const float* __restrict__ s3,
           const float* __restrict__ s4, const float* __restrict__ s5,
           unsigned short* __restrict__ dst) {
    const size_t i8 = ((size_t)blockIdx.x * 256 + threadIdx.x) * 8;
    if (i8 >= 12907520u) return;
    const float* sp; size_t loc;
    if (i8 < 11523072u)      { sp = s0; loc = i8; }
    else if (i8 < 12547072u) { sp = s1; loc = i8 - 11523072u; }
    else if (i8 < 12612608u) { sp = s2; loc = i8 - 12547072u; }
    else if (i8 < 12645376u) { sp = s3; loc = i8 - 12612608u; }
    else if (i8 < 12776448u) { sp = s4; loc = i8 - 12645376u; }
    else                     { sp = s5; loc = i8 - 12776448u; }
    f32x4 a = *(const f32x4*)(sp + loc);
    f32x4 b = *(const f32x4*)(sp + loc + 4);
    bf16x8 r;
    r[0] = f2bf(a[0]); r[1] = f2bf(a[1]); r[2] = f2bf(a[2]); r[3] = f2bf(a[3]);
    r[4] = f2bf(b[0]); r[5] = f2bf(b[1]); r[6] = f2bf(b[2]); r[7] = f2bf(b[3]);
    *(bf16x8*)(dst + i8) = r;
}

// ---------------------------------------------------------------------------
// bf16 GEMM: C = A[M,K] @ B[N,K]^T + bias[N]. BM=BN=128, BK=32, 4 waves 2x2.
// MODE 0: C f32 row-major [M,N] (R4-proven epilogue).
// MODE 1: C bf16 -> valueT[n][h][pix][64]; per-wave LDS-transpose epilogue:
//         wave owns 64pix x 64ch (head = bn*2+wn), [64][68]-padded tile,
//         bank-conflict-free b16 writes, then coalesced bf16x4 stores.
// ---------------------------------------------------------------------------
template<int MODE>
__global__ __launch_bounds__(256)
void gemm_bf16_tn(const unsigned short* __restrict__ A,
                  const unsigned short* __restrict__ B,
                  const float* __restrict__ bias, void* __restrict__ Cv,
                  int M, int N, int K) {
    constexpr int TILE_B = 4 * 64 * 68 * 2;             // 34816
    constexpr int SMEM_B = (MODE == 1 && TILE_B > 20480) ? TILE_B : 20480;
    __shared__ __align__(16) char smem[SMEM_B];
    unsigned short (*As)[40] = (unsigned short (*)[40])smem;
    unsigned short (*Bs)[40] = (unsigned short (*)[40])(smem + 10240);

    const int bm = blockIdx.x, bn = blockIdx.y;
    const int tid  = threadIdx.x;
    const int lane = tid & 63;
    const int wid  = tid >> 6;
    const int wm   = wid >> 1, wn = wid & 1;

    const int srow = tid >> 1;
    const int scol = (tid & 1) << 4;   // 0 or 16

    int arow = bm * 128 + srow; if (arow > M - 1) arow = M - 1;   // tail clamp
    const unsigned short* pa = A + (size_t)arow * K + scol;
    const unsigned short* pb = B + (size_t)(bn * 128 + srow) * K + scol;

    f32x4 acc[4][4] = {};
    const int k8 = (lane >> 4) << 3;
    const int fr = lane & 15;
    const int fq = lane >> 4;

    for (int k0 = 0; k0 < K; k0 += 32) {
        bf16x8 a0 = *(const bf16x8*)(pa + k0);
        bf16x8 a1 = *(const bf16x8*)(pa + k0 + 8);
        bf16x8 b0 = *(const bf16x8*)(pb + k0);
        bf16x8 b1 = *(const bf16x8*)(pb + k0 + 8);

        __syncthreads();   // previous iteration's frag reads done
        *(bf16x8*)&As[srow][scol]     = a0;
        *(bf16x8*)&As[srow][scol + 8] = a1;
        *(bf16x8*)&Bs[srow][scol]     = b0;
        *(bf16x8*)&Bs[srow][scol + 8] = b1;
        __syncthreads();

        bf16x8 af[4], bfr[4];
#pragma unroll
        for (int m = 0; m < 4; m++)
            af[m] = *(const bf16x8*)&As[wm * 64 + m * 16 + fr][k8];
#pragma unroll
        for (int nn = 0; nn < 4; nn++)
            bfr[nn] = *(const bf16x8*)&Bs[wn * 64 + nn * 16 + fr][k8];
#pragma unroll
        for (int m = 0; m < 4; m++)
#pragma unroll
            for (int nn = 0; nn < 4; nn++)
                acc[m][nn] = __builtin_amdgcn_mfma_f32_16x16x32_bf16(
                    af[m], bfr[nn], acc[m][nn], 0, 0, 0);
    }

    if (MODE == 0) {
        // C/D layout (m89-verified): col = lane&15, row = (lane>>4)*4 + j
        const int crow0 = bm * 128 + wm * 64 + fq * 4;
        const int ccol0 = bn * 128 + wn * 64 + fr;
#pragma unroll
        for (int m = 0; m < 4; m++) {
#pragma unroll
            for (int nn = 0; nn < 4; nn++) {
                const int col = ccol0 + nn * 16;
                const float bv = bias[col];
#pragma unroll
                for (int j = 0; j < 4; j++) {
                    const int row = crow0 + m * 16 + j;
                    if (row < M) ((float*)Cv)[(size_t)row * N + col] = acc[m][nn][j] + bv;
                }
            }
        }
    } else {
        __syncthreads();   // all waves done reading As/Bs before repurposing
        unsigned short* tile = (unsigned short*)smem + (size_t)wid * (64 * 68);
        const int hh = bn * 2 + wn;                 // head, uniform per wave
        float bvs[4];
#pragma unroll
        for (int nn = 0; nn < 4; nn++) bvs[nn] = bias[hh * 64 + nn * 16 + fr];
        // tile[pix_local][ch]: pix_local = m*16+fq*4+j, ch = nn*16+fr.
        // banks: (pix*34 + fr/2) %32 -> fq*8 + fr/2 = all 32 banks, 2 lanes each.
#pragma unroll
        for (int m = 0; m < 4; m++)
#pragma unroll
            for (int nn = 0; nn < 4; nn++)
#pragma unroll
                for (int j = 0; j < 4; j++)
                    tile[(m * 16 + fq * 4 + j) * 68 + nn * 16 + fr] =
                        f2bf(acc[m][nn][j] + bvs[nn]);
        __syncthreads();
        // coalesced store: lane covers 8B of channels; 4 pixels/instr, 512B contig
        unsigned short* VT = (unsigned short*)Cv;
        const int q4 = (lane & 15) * 4;
        const int prow = lane >> 4;                 // 0..3
#pragma unroll
        for (int it = 0; it < 16; ++it) {
            const int pl = it * 4 + prow;           // local pixel 0..63
            const int pixg = bm * 128 + wm * 64 + pl;
            if (pixg < M) {
                const int n = pixg / 11253;
                const int pix = pixg - n * 11253;
                bf16x4 v = *(const bf16x4*)&tile[pl * 68 + q4];
                *(bf16x4*)(VT + ((size_t)(n * 8 + hh) * 11253 + pix) * 64 + q4) = v;
            }
        }
    }
}

// ---------------------------------------------------------------------------
// Sampling (R6-proven): one wave per (n, q, h). Scalar softmax reduction;
// lane-parallel bilinear metadata (lane l: point l&15, x-corner group l>>4&1);
// gather loop broadcasts meta via __shfl; 2 coalesced row-gathers + 4 FMA/pt.
// ---------------------------------------------------------------------------
__global__ __launch_bounds__(256)
void sample_k(const unsigned short* __restrict__ valueT, // [4][8][11253][64] bf16
              const float* __restrict__ refp,            // [4][1000][4][2]
              const float* __restrict__ off,             // [4][1000][256]
              const float* __restrict__ logits,          // [4][1000][128]
              unsigned int* __restrict__ msout)          // [4][1000][256] dwords
{
    const int id   = __builtin_amdgcn_readfirstlane(blockIdx.x * 4 + (threadIdx.x >> 6));
    const int lane = threadIdx.x & 63;
    const int g    = lane >> 5;          // x-corner group (0: xb, 1: xb+1)

    const int n = id / 8000;
    const int r = id - n * 8000;
    const int q = r >> 3;
    const int h = r & 7;
    const int nq = n * 1000 + q;

    // softmax reduction over the 16 points (scalar, uniform loads)
    const float* lgp = logits + (size_t)nq * 128 + h * 16;
    float mx = lgp[0];
#pragma unroll
    for (int pp = 1; pp < 16; pp++) mx = fmaxf(mx, lgp[pp]);
    float s = 0.f;
#pragma unroll
    for (int pp = 0; pp < 16; pp++) s += __expf(lgp[pp] - mx);

    // per-point metadata on lane groups of 16 (lanes 0-31 are the sources)
    const int p  = lane & 15;
    const int lv = p >> 2;
    const int W  = lv == 0 ? 92 : lv == 1 ? 46 : lv == 2 ? 23 : 12;  // H == W
    const int st = lv == 0 ? 0 : lv == 1 ? 8464 : lv == 2 ? 10580 : 11109;

    const float a  = __expf(lgp[p] - mx) / s;
    const float rx = refp[(size_t)nq * 8 + lv * 2 + 0];
    const float ry = refp[(size_t)nq * 8 + lv * 2 + 1];
    const float ox = off[(size_t)nq * 256 + h * 32 + p * 2 + 0];
    const float oy = off[(size_t)nq * 256 + h * 32 + p * 2 + 1];

    const float x = rx * (float)W + ox - 0.5f;
    const float y = ry * (float)W + oy - 0.5f;
    const float xf = floorf(x), yf = floorf(y);
    const int x0 = (int)xf, y0 = (int)yf;
    const float lx = x - xf, ly = y - yf;
    const int xb = min(max(x0, 0), W - 2);
    const int yb = min(max(y0, 0), W - 2);
    // weight of pixel xb+dx: ==x0 -> 1-lx, ==x0+1 -> lx, else 0 (same for y)
    const float wx0 = (xb     == x0) ? (1.f - lx) : ((xb     == x0 + 1) ? lx : 0.f);
    const float wx1 = (xb + 1 == x0) ? (1.f - lx) : ((xb + 1 == x0 + 1) ? lx : 0.f);
    const float wy0 = (yb     == y0) ? (1.f - ly) : ((yb     == y0 + 1) ? ly : 0.f);
    const float wy1 = (yb + 1 == y0) ? (1.f - ly) : ((yb + 1 == y0 + 1) ? ly : 0.f);
    const int idx0v = st + yb * W + xb;
    const int idx1v = idx0v + W;
    const float wxs = (lane & 16) ? wx1 : wx0;   // lane group picks its x-corner
    const float wav = a * wxs * wy0;
    const float wbv = a * wxs * wy1;

    const unsigned int* vb =
        (const unsigned int*)valueT + ((size_t)n * 8 + h) * 11253 * 32;

    float acc0 = 0.f, acc1 = 0.f;
    const int srcb = g << 4;
#pragma unroll
    for (int pp = 0; pp < 16; pp++) {
        const int src = pp + srcb;           // lane pp (g=0) or pp+16 (g=1)
        const int   i0 = __shfl(idx0v, src);
        const int   i1 = __shfl(idx1v, src);
        const float w0 = __shfl(wav,   src);
        const float w1 = __shfl(wbv,   src);
        const unsigned d0 = vb[i0 * 32 + lane];   // lane>=32 reads pixel+1
        const unsigned d1 = vb[i1 * 32 + lane];
        acc0 = fmaf(w0, bflo(d0), acc0);
        acc1 = fmaf(w0, bfhi(d0), acc1);
        acc0 = fmaf(w1, bflo(d1), acc0);
        acc1 = fmaf(w1, bfhi(d1), acc1);
    }

    acc0 += __shfl(acc0, lane ^ 32);
    acc1 += __shfl(acc1, lane ^ 32);
    if (lane < 32) {
        const unsigned u = (unsigned)f2bf(acc0) | ((unsigned)f2bf(acc1) << 16);
        msout[(size_t)nq * 256 + h * 32 + (lane & 31)] = u;
    }
}

// ---------------------------------------------------------------------------
extern "C" void kernel_launch(void* const* d_in, const int* in_sizes, int n_in,
                              void* d_out, int out_size, void* d_ws, size_t ws_size,
                              hipStream_t stream) {
    (void)in_sizes; (void)n_in; (void)out_size; (void)ws_size;

    const float* query  = (const float*)d_in[0];
    const float* refp   = (const float*)d_in[1];
    const float* inpf   = (const float*)d_in[2];
    const float* W_off  = (const float*)d_in[5];
    const float* b_off  = (const float*)d_in[6];
    const float* W_attn = (const float*)d_in[7];
    const float* b_attn = (const float*)d_in[8];
    const float* W_val  = (const float*)d_in[9];
    const float* b_val  = (const float*)d_in[10];
    const float* W_out  = (const float*)d_in[11];
    const float* b_out  = (const float*)d_in[12];
    float* out = (float*)d_out;

    char* ws = (char*)d_ws;
    unsigned short* bf = (unsigned short*)ws;                    // 25,815,040 B
    unsigned short* inpfb   = bf;
    unsigned short* queryb  = bf + 11523072;
    unsigned short* W_offb  = bf + 12547072;
    unsigned short* W_attnb = bf + 12612608;
    unsigned short* W_valb  = bf + 12645376;
    unsigned short* W_outb  = bf + 12776448;
    unsigned short* valueT  = (unsigned short*)(ws + 25815040);  // 46,092,288 B
    float* offb   = (float*)(ws + 71907328);                     //  4,096,000 B
    float* logits = (float*)(ws + 76003328);                     //  2,048,000 B
    unsigned int* msoutu = (unsigned int*)(ws + 78051328);       //  4,096,000 B
    unsigned short* msoutb = (unsigned short*)msoutu;

    // 0. convert everything to bf16
    cvt_k<<<6303, 256, 0, stream>>>(inpf, query, W_off, W_attn, W_val, W_out, bf);
    // 1. value projection -> bf16 transposed [n][h][pix][64]
    gemm_bf16_tn<1><<<dim3(352, 4), 256, 0, stream>>>(inpfb, W_valb, b_val, valueT, 45012, 512, 256);
    // 2. offsets
    gemm_bf16_tn<0><<<dim3(32, 2), 256, 0, stream>>>(queryb, W_offb, b_off, offb, 4000, 256, 256);
    // 3. attention logits
    gemm_bf16_tn<0><<<dim3(32, 1), 256, 0, stream>>>(queryb, W_attnb, b_attn, logits, 4000, 128, 256);
    // 4. sampling (fused softmax), msout bf16
    sample_k<<<8000, 256, 0, stream>>>(valueT, refp, offb, logits, msoutu);
    // 5. output projection
    gemm_bf16_tn<0><<<dim3(32, 2), 256, 0, stream>>>(msoutb, W_outb, b_out, out, 4000, 256, 512);
}

// Round 8
// 113.594 us; speedup vs baseline: 1.7652x; 1.0105x over previous
//
#include <hip/hip_runtime.h>

// ---------------------------------------------------------------------------
// MS Deformable Attention (Deformable-DETR), MI355X gfx950.
//   0. cvt    : all f32 operands -> bf16 (one streaming kernel)
//   1. valueT = bf16( input_flatten @ W_val^T + b_val ) -> [n][h][pix][64]
//   2. off    = query @ W_off^T  + b_off   [4000 x 256] f32
//   3. logits = query @ W_attn^T + b_attn  [4000 x 128] f32
//   4. msout  = bilinear-sample(valueT, loc, softmax(logits)) -> bf16
//   5. out    = msout @ W_out^T + b_out    [4000 x 256] f32
// GEMM main loop upgraded to m97 structure: BK=64, global_load_lds(16B)
// staging with pre-swizzled source + XOR'd ds_read_b128 (R2-exonerated).
// Epilogues (MODE0 / MODE1 LDS-transpose), sample_k, cvt_k = R7 verbatim.
// ---------------------------------------------------------------------------

typedef __attribute__((ext_vector_type(4))) float f32x4;
typedef __attribute__((ext_vector_type(8))) short bf16x8;
typedef __attribute__((ext_vector_type(4))) short bf16x4;

static __device__ __forceinline__ unsigned short f2bf(float f) {
    unsigned u = __builtin_bit_cast(unsigned, f);
    u += 0x7FFFu + ((u >> 16) & 1u);   // round-to-nearest-even
    return (unsigned short)(u >> 16);
}
static __device__ __forceinline__ float bflo(unsigned d) {
    return __builtin_bit_cast(float, d << 16);
}
static __device__ __forceinline__ float bfhi(unsigned d) {
    return __builtin_bit_cast(float, d & 0xffff0000u);
}
static __device__ __forceinline__ void gload_lds16(const void* g, void* l) {
    __builtin_amdgcn_global_load_lds(
        (const __attribute__((address_space(1))) void*)g,
        (__attribute__((address_space(3))) void*)l, 16, 0, 0);
}

// ---------------------------------------------------------------------------
// f32 -> bf16 conversion of all operands into one packed buffer.
//   inpf 0 | query 11523072 | W_off 12547072 | W_attn 12612608
//   | W_val 12645376 | W_out 12776448 | total 12907520
// ---------------------------------------------------------------------------
__global__ __launch_bounds__(256)
void cvt_k(const float* __restrict__ s0, const float* __restrict__ s1,
           const float* __restrict__ s2, const float* __restrict__ s3,
           const float* __restrict__ s4, const float* __restrict__ s5,
           unsigned short* __restrict__ dst) {
    const size_t i8 = ((size_t)blockIdx.x * 256 + threadIdx.x) * 8;
    if (i8 >= 12907520u) return;
    const float* sp; size_t loc;
    if (i8 < 11523072u)      { sp = s0; loc = i8; }
    else if (i8 < 12547072u) { sp = s1; loc = i8 - 11523072u; }
    else if (i8 < 12612608u) { sp = s2; loc = i8 - 12547072u; }
    else if (i8 < 12645376u) { sp = s3; loc = i8 - 12612608u; }
    else if (i8 < 12776448u) { sp = s4; loc = i8 - 12645376u; }
    else                     { sp = s5; loc = i8 - 12776448u; }
    f32x4 a = *(const f32x4*)(sp + loc);
    f32x4 b = *(const f32x4*)(sp + loc + 4);
    bf16x8 r;
    r[0] = f2bf(a[0]); r[1] = f2bf(a[1]); r[2] = f2bf(a[2]); r[3] = f2bf(a[3]);
    r[4] = f2bf(b[0]); r[5] = f2bf(b[1]); r[6] = f2bf(b[2]); r[7] = f2bf(b[3]);
    *(bf16x8*)(dst + i8) = r;
}

// ---------------------------------------------------------------------------
// bf16 GEMM: C = A[M,K] @ B[N,K]^T + bias[N]. BM=BN=128, BK=64, 4 waves 2x2.
// Staging: global_load_lds 16B, linear LDS [128][64], source col pre-XOR'd
// (b16 ^= row&7) so the XOR'd ds_read_b128 lands conflict-soft (2-way).
// MODE 0: C f32 row-major [M,N].
// MODE 1: C bf16 -> valueT[n][h][pix][64] via per-wave LDS-transpose epilogue.
// ---------------------------------------------------------------------------
template<int MODE>
__global__ __launch_bounds__(256)
void gemm_bf16_tn(const unsigned short* __restrict__ A,
                  const unsigned short* __restrict__ B,
                  const float* __restrict__ bias, void* __restrict__ Cv,
                  int M, int N, int K) {
    constexpr int MAIN_B = 2 * 128 * 64 * 2;            // 32768 (As+Bs)
    constexpr int TILE_B = 4 * 64 * 68 * 2;             // 34816 (MODE1 epilogue)
    constexpr int SMEM_B = (MODE == 1) ? TILE_B : MAIN_B;
    __shared__ __align__(16) char smem[SMEM_B];

    const int tid = threadIdx.x, lane = tid & 63, w = tid >> 6;
    const int wm = w >> 1, wn = w & 1;
    const int bm = blockIdx.x, bn = blockIdx.y;

    // staging map: LDS byte (j*4096 + w*1024 + lane*16) -> row j*32+w*8+(lane>>3),
    // 16B-block (lane&7). Source block pre-XOR'd by row&7 (= lane>>3 & 7).
    const int r8 = lane >> 3;
    const int colsrc = (((lane & 7) ^ r8) << 4);
    const char* pa[4]; const char* pb[4];
#pragma unroll
    for (int j = 0; j < 4; j++) {
        int ra = bm * 128 + j * 32 + w * 8 + r8; ra = ra < M ? ra : M - 1;
        int rb = bn * 128 + j * 32 + w * 8 + r8; rb = rb < N ? rb : N - 1;
        pa[j] = (const char*)A + (size_t)ra * ((size_t)K * 2) + colsrc;
        pb[j] = (const char*)B + (size_t)rb * ((size_t)K * 2) + colsrc;
    }
    const int ldso = w << 10;
    const int NT = K >> 6;

    f32x4 acc[4][4] = {};
    const int fr = lane & 15, fq = lane >> 4;
    const int k8b = fq << 4;            // fq*8 shorts = fq*16 bytes
    const int swzR = (fr & 7) << 4;     // read-side XOR (row&7 == fr&7)

#pragma unroll
    for (int j = 0; j < 4; j++) {
        gload_lds16(pa[j], smem + j * 4096 + ldso);
        gload_lds16(pb[j], smem + 16384 + j * 4096 + ldso);
    }

    for (int t = 0; t < NT; ++t) {
        __syncthreads();   // drains vmcnt(0): staged tile visible
#pragma unroll
        for (int kk = 0; kk < 2; ++kk) {
            const int ko = ((kk << 6) + k8b) ^ swzR;
            bf16x8 af[4], bv[4];
#pragma unroll
            for (int m = 0; m < 4; m++)
                af[m] = *(const bf16x8*)(smem + ((wm * 64 + m * 16 + fr) << 7) + ko);
#pragma unroll
            for (int nn = 0; nn < 4; nn++)
                bv[nn] = *(const bf16x8*)(smem + 16384 + ((wn * 64 + nn * 16 + fr) << 7) + ko);
#pragma unroll
            for (int m = 0; m < 4; m++)
#pragma unroll
                for (int nn = 0; nn < 4; nn++)
                    acc[m][nn] = __builtin_amdgcn_mfma_f32_16x16x32_bf16(
                        af[m], bv[nn], acc[m][nn], 0, 0, 0);
        }
        __syncthreads();   // all reads of this tile done before restage
        if (t + 1 < NT) {
            const int off = (t + 1) << 7;   // 128 B per BK-tile within a row
#pragma unroll
            for (int j = 0; j < 4; j++) {
                gload_lds16(pa[j] + off, smem + j * 4096 + ldso);
                gload_lds16(pb[j] + off, smem + 16384 + j * 4096 + ldso);
            }
        }
    }

    if (MODE == 0) {
        // C/D layout (m89-verified): col = lane&15, row = (lane>>4)*4 + j
        float* C = (float*)Cv;
        const int crow0 = bm * 128 + wm * 64 + fq * 4;
        const int ccol0 = bn * 128 + wn * 64 + fr;
#pragma unroll
        for (int m = 0; m < 4; m++) {
#pragma unroll
            for (int nn = 0; nn < 4; nn++) {
                const int col = ccol0 + nn * 16;
                const float bv2 = bias[col];
#pragma unroll
                for (int j = 0; j < 4; j++) {
                    const int row = crow0 + m * 16 + j;
                    if (row < M) C[(size_t)row * N + col] = acc[m][nn][j] + bv2;
                }
            }
        }
    } else {
        // per-wave LDS transpose epilogue (R7-proven); last __syncthreads()
        // already guarantees all waves finished reading As/Bs.
        unsigned short* tile = (unsigned short*)smem + (size_t)w * (64 * 68);
        const int hh = bn * 2 + wn;                 // head, uniform per wave
        float bvs[4];
#pragma unroll
        for (int nn = 0; nn < 4; nn++) bvs[nn] = bias[hh * 64 + nn * 16 + fr];
#pragma unroll
        for (int m = 0; m < 4; m++)
#pragma unroll
            for (int nn = 0; nn < 4; nn++)
#pragma unroll
                for (int j = 0; j < 4; j++)
                    tile[(m * 16 + fq * 4 + j) * 68 + nn * 16 + fr] =
                        f2bf(acc[m][nn][j] + bvs[nn]);
        __syncthreads();
        unsigned short* VT = (unsigned short*)Cv;
        const int q4 = (lane & 15) * 4;
        const int prow = lane >> 4;                 // 0..3
#pragma unroll
        for (int it = 0; it < 16; ++it) {
            const int pl = it * 4 + prow;           // local pixel 0..63
            const int pixg = bm * 128 + wm * 64 + pl;
            if (pixg < M) {
                const int n = pixg / 11253;
                const int pix = pixg - n * 11253;
                bf16x4 v = *(const bf16x4*)&tile[pl * 68 + q4];
                *(bf16x4*)(VT + ((size_t)(n * 8 + hh) * 11253 + pix) * 64 + q4) = v;
            }
        }
    }
}

// ---------------------------------------------------------------------------
// Sampling (R6/R7-proven): one wave per (n, q, h). Scalar softmax reduction;
// lane-parallel bilinear metadata (lane l: point l&15, x-corner group);
// gather loop broadcasts meta via __shfl; 2 coalesced row-gathers + 4 FMA/pt.
// ---------------------------------------------------------------------------
__global__ __launch_bounds__(256)
void sample_k(const unsigned short* __restrict__ valueT, // [4][8][11253][64] bf16
              const float* __restrict__ refp,            // [4][1000][4][2]
              const float* __restrict__ off,             // [4][1000][256]
              const float* __restrict__ logits,          // [4][1000][128]
              unsigned int* __restrict__ msout)          // [4][1000][256] dwords
{
    const int id   = __builtin_amdgcn_readfirstlane(blockIdx.x * 4 + (threadIdx.x >> 6));
    const int lane = threadIdx.x & 63;
    const int g    = lane >> 5;          // x-corner group (0: xb, 1: xb+1)

    const int n = id / 8000;
    const int r = id - n * 8000;
    const int q = r >> 3;
    const int h = r & 7;
    const int nq = n * 1000 + q;

    // softmax reduction over the 16 points (scalar, uniform loads)
    const float* lgp = logits + (size_t)nq * 128 + h * 16;
    float mx = lgp[0];
#pragma unroll
    for (int pp = 1; pp < 16; pp++) mx = fmaxf(mx, lgp[pp]);
    float s = 0.f;
#pragma unroll
    for (int pp = 0; pp < 16; pp++) s += __expf(lgp[pp] - mx);

    // per-point metadata on lane groups of 16 (lanes 0-31 are the sources)
    const int p  = lane & 15;
    const int lv = p >> 2;
    const int W  = lv == 0 ? 92 : lv == 1 ? 46 : lv == 2 ? 23 : 12;  // H == W
    const int st = lv == 0 ? 0 : lv == 1 ? 8464 : lv == 2 ? 10580 : 11109;

    const float a  = __expf(lgp[p] - mx) / s;
    const float rx = refp[(size_t)nq * 8 + lv * 2 + 0];
    const float ry = refp[(size_t)nq * 8 + lv * 2 + 1];
    const float ox = off[(size_t)nq * 256 + h * 32 + p * 2 + 0];
    const float oy = off[(size_t)nq * 256 + h * 32 + p * 2 + 1];

    const float x = rx * (float)W + ox - 0.5f;
    const float y = ry * (float)W + oy - 0.5f;
    const float xf = floorf(x), yf = floorf(y);
    const int x0 = (int)xf, y0 = (int)yf;
    const float lx = x - xf, ly = y - yf;
    const int xb = min(max(x0, 0), W - 2);
    const int yb = min(max(y0, 0), W - 2);
    const float wx0 = (xb     == x0) ? (1.f - lx) : ((xb     == x0 + 1) ? lx : 0.f);
    const float wx1 = (xb + 1 == x0) ? (1.f - lx) : ((xb + 1 == x0 + 1) ? lx : 0.f);
    const float wy0 = (yb     == y0) ? (1.f - ly) : ((yb     == y0 + 1) ? ly : 0.f);
    const float wy1 = (yb + 1 == y0) ? (1.f - ly) : ((yb + 1 == y0 + 1) ? ly : 0.f);
    const int idx0v = st + yb * W + xb;
    const int idx1v = idx0v + W;
    const float wxs = (lane & 16) ? wx1 : wx0;   // lane group picks its x-corner
    const float wav = a * wxs * wy0;
    const float wbv = a * wxs * wy1;

    const unsigned int* vb =
        (const unsigned int*)valueT + ((size_t)n * 8 + h) * 11253 * 32;

    float acc0 = 0.f, acc1 = 0.f;
    const int srcb = g << 4;
#pragma unroll
    for (int pp = 0; pp < 16; pp++) {
        const int src = pp + srcb;           // lane pp (g=0) or pp+16 (g=1)
        const int   i0 = __shfl(idx0v, src);
        const int   i1 = __shfl(idx1v, src);
        const float w0 = __shfl(wav,   src);
        const float w1 = __shfl(wbv,   src);
        const unsigned d0 = vb[i0 * 32 + lane];   // lane>=32 reads pixel+1
        const unsigned d1 = vb[i1 * 32 + lane];
        acc0 = fmaf(w0, bflo(d0), acc0);
        acc1 = fmaf(w0, bfhi(d0), acc1);
        acc0 = fmaf(w1, bflo(d1), acc0);
        acc1 = fmaf(w1, bfhi(d1), acc1);
    }

    acc0 += __shfl(acc0, lane ^ 32);
    acc1 += __shfl(acc1, lane ^ 32);
    if (lane < 32) {
        const unsigned u = (unsigned)f2bf(acc0) | ((unsigned)f2bf(acc1) << 16);
        msout[(size_t)nq * 256 + h * 32 + (lane & 31)] = u;
    }
}

// ---------------------------------------------------------------------------
extern "C" void kernel_launch(void* const* d_in, const int* in_sizes, int n_in,
                              void* d_out, int out_size, void* d_ws, size_t ws_size,
                              hipStream_t stream) {
    (void)in_sizes; (void)n_in; (void)out_size; (void)ws_size;

    const float* query  = (const float*)d_in[0];
    const float* refp   = (const float*)d_in[1];
    const float* inpf   = (const float*)d_in[2];
    const float* W_off  = (const float*)d_in[5];
    const float* b_off  = (const float*)d_in[6];
    const float* W_attn = (const float*)d_in[7];
    const float* b_attn = (const float*)d_in[8];
    const float* W_val  = (const float*)d_in[9];
    const float* b_val  = (const float*)d_in[10];
    const float* W_out  = (const float*)d_in[11];
    const float* b_out  = (const float*)d_in[12];
    float* out = (float*)d_out;

    char* ws = (char*)d_ws;
    unsigned short* bf = (unsigned short*)ws;                    // 25,815,040 B
    unsigned short* inpfb   = bf;
    unsigned short* queryb  = bf + 11523072;
    unsigned short* W_offb  = bf + 12547072;
    unsigned short* W_attnb = bf + 12612608;
    unsigned short* W_valb  = bf + 12645376;
    unsigned short* W_outb  = bf + 12776448;
    unsigned short* valueT  = (unsigned short*)(ws + 25815040);  // 46,092,288 B
    float* offb   = (float*)(ws + 71907328);                     //  4,096,000 B
    float* logits = (float*)(ws + 76003328);                     //  2,048,000 B
    unsigned int* msoutu = (unsigned int*)(ws + 78051328);       //  4,096,000 B
    unsigned short* msoutb = (unsigned short*)msoutu;

    // 0. convert everything to bf16
    cvt_k<<<6303, 256, 0, stream>>>(inpf, query, W_off, W_attn, W_val, W_out, bf);
    // 1. value projection -> bf16 transposed [n][h][pix][64]
    gemm_bf16_tn<1><<<dim3(352, 4), 256, 0, stream>>>(inpfb, W_valb, b_val, valueT, 45012, 512, 256);
    // 2. offsets
    gemm_bf16_tn<0><<<dim3(32, 2), 256, 0, stream>>>(queryb, W_offb, b_off, offb, 4000, 256, 256);
    // 3. attention logits
    gemm_bf16_tn<0><<<dim3(32, 1), 256, 0, stream>>>(queryb, W_attnb, b_attn, logits, 4000, 128, 256);
    // 4. sampling (fused softmax), msout bf16
    sample_k<<<8000, 256, 0, stream>>>(valueT, refp, offb, logits, msoutu);
    // 5. output projection
    gemm_bf16_tn<0><<<dim3(32, 2), 256, 0, stream>>>(msoutb, W_outb, b_out, out, 4000, 256, 512);
}

// Round 9
// 101.153 us; speedup vs baseline: 1.9822x; 1.1230x over previous
//
#include <hip/hip_runtime.h>

// ---------------------------------------------------------------------------
// MS Deformable Attention (Deformable-DETR), MI355X gfx950.
//   0. cvt    : all f32 operands -> bf16 (one streaming kernel)
//   1. valueT = bf16( input_flatten @ W_val^T + b_val ) -> [n][h][pix][64]
//   2. fused  = query @ [W_off;W_attn]^T + [b_off;b_attn]  [4000 x 384] f32
//   3. msout  = bilinear-sample(valueT, loc, softmax(logits)) -> bf16
//      (XCD-pinned (n,h) slice mapping for L2-resident gathers)
//   4. out    = msout @ W_out^T + b_out    [4000 x 256] f32
// vs R8: off+logits GEMMs merged (MODE2, dual-bias); sample_k block mapping
// XCD-pinned; everything else verbatim.
// ---------------------------------------------------------------------------

typedef __attribute__((ext_vector_type(4))) float f32x4;
typedef __attribute__((ext_vector_type(8))) short bf16x8;
typedef __attribute__((ext_vector_type(4))) short bf16x4;

static __device__ __forceinline__ unsigned short f2bf(float f) {
    unsigned u = __builtin_bit_cast(unsigned, f);
    u += 0x7FFFu + ((u >> 16) & 1u);   // round-to-nearest-even
    return (unsigned short)(u >> 16);
}
static __device__ __forceinline__ float bflo(unsigned d) {
    return __builtin_bit_cast(float, d << 16);
}
static __device__ __forceinline__ float bfhi(unsigned d) {
    return __builtin_bit_cast(float, d & 0xffff0000u);
}
static __device__ __forceinline__ void gload_lds16(const void* g, void* l) {
    __builtin_amdgcn_global_load_lds(
        (const __attribute__((address_space(1))) void*)g,
        (__attribute__((address_space(3))) void*)l, 16, 0, 0);
}

// ---------------------------------------------------------------------------
// f32 -> bf16 conversion of all operands into one packed buffer.
//   inpf 0 | query 11523072 | W_off 12547072 | W_attn 12612608
//   | W_val 12645376 | W_out 12776448 | total 12907520
// (W_off and W_attn are adjacent -> they form one [384 x 256] matrix.)
// ---------------------------------------------------------------------------
__global__ __launch_bounds__(256)
void cvt_k(const float* __restrict__ s0, const float* __restrict__ s1,
           const float* __restrict__ s2, const float* __restrict__ s3,
           const float* __restrict__ s4, const float* __restrict__ s5,
           unsigned short* __restrict__ dst) {
    const size_t i8 = ((size_t)blockIdx.x * 256 + threadIdx.x) * 8;
    if (i8 >= 12907520u) return;
    const float* sp; size_t loc;
    if (i8 < 11523072u)      { sp = s0; loc = i8; }
    else if (i8 < 12547072u) { sp = s1; loc = i8 - 11523072u; }
    else if (i8 < 12612608u) { sp = s2; loc = i8 - 12547072u; }
    else if (i8 < 12645376u) { sp = s3; loc = i8 - 12612608u; }
    else if (i8 < 12776448u) { sp = s4; loc = i8 - 12645376u; }
    else                     { sp = s5; loc = i8 - 12776448u; }
    f32x4 a = *(const f32x4*)(sp + loc);
    f32x4 b = *(const f32x4*)(sp + loc + 4);
    bf16x8 r;
    r[0] = f2bf(a[0]); r[1] = f2bf(a[1]); r[2] = f2bf(a[2]); r[3] = f2bf(a[3]);
    r[4] = f2bf(b[0]); r[5] = f2bf(b[1]); r[6] = f2bf(b[2]); r[7] = f2bf(b[3]);
    *(bf16x8*)(dst + i8) = r;
}

// ---------------------------------------------------------------------------
// bf16 GEMM: C = A[M,K] @ B[N,K]^T + bias. BM=BN=128, BK=64, 4 waves 2x2.
// Staging: global_load_lds 16B, linear LDS, source col pre-XOR'd (b16 ^= row&7).
// MODE 0: C f32 row-major [M,N], bias[col].
// MODE 1: C bf16 -> valueT[n][h][pix][64] via per-wave LDS-transpose epilogue.
// MODE 2: C f32 row-major [M,N], dual bias: col<256 -> bias, else bias2[col-256].
// ---------------------------------------------------------------------------
template<int MODE>
__global__ __launch_bounds__(256)
void gemm_bf16_tn(const unsigned short* __restrict__ A,
                  const unsigned short* __restrict__ B,
                  const float* __restrict__ bias, const float* __restrict__ bias2,
                  void* __restrict__ Cv, int M, int N, int K) {
    constexpr int MAIN_B = 2 * 128 * 64 * 2;            // 32768 (As+Bs)
    constexpr int TILE_B = 4 * 64 * 68 * 2;             // 34816 (MODE1 epilogue)
    constexpr int SMEM_B = (MODE == 1) ? TILE_B : MAIN_B;
    __shared__ __align__(16) char smem[SMEM_B];

    const int tid = threadIdx.x, lane = tid & 63, w = tid >> 6;
    const int wm = w >> 1, wn = w & 1;
    const int bm = blockIdx.x, bn = blockIdx.y;

    // staging map: LDS byte (j*4096 + w*1024 + lane*16) -> row j*32+w*8+(lane>>3),
    // 16B-block (lane&7). Source block pre-XOR'd by row&7 (= lane>>3 & 7).
    const int r8 = lane >> 3;
    const int colsrc = (((lane & 7) ^ r8) << 4);
    const char* pa[4]; const char* pb[4];
#pragma unroll
    for (int j = 0; j < 4; j++) {
        int ra = bm * 128 + j * 32 + w * 8 + r8; ra = ra < M ? ra : M - 1;
        int rb = bn * 128 + j * 32 + w * 8 + r8; rb = rb < N ? rb : N - 1;
        pa[j] = (const char*)A + (size_t)ra * ((size_t)K * 2) + colsrc;
        pb[j] = (const char*)B + (size_t)rb * ((size_t)K * 2) + colsrc;
    }
    const int ldso = w << 10;
    const int NT = K >> 6;

    f32x4 acc[4][4] = {};
    const int fr = lane & 15, fq = lane >> 4;
    const int k8b = fq << 4;            // fq*8 shorts = fq*16 bytes
    const int swzR = (fr & 7) << 4;     // read-side XOR (row&7 == fr&7)

#pragma unroll
    for (int j = 0; j < 4; j++) {
        gload_lds16(pa[j], smem + j * 4096 + ldso);
        gload_lds16(pb[j], smem + 16384 + j * 4096 + ldso);
    }

    for (int t = 0; t < NT; ++t) {
        __syncthreads();   // drains vmcnt(0): staged tile visible
#pragma unroll
        for (int kk = 0; kk < 2; ++kk) {
            const int ko = ((kk << 6) + k8b) ^ swzR;
            bf16x8 af[4], bv[4];
#pragma unroll
            for (int m = 0; m < 4; m++)
                af[m] = *(const bf16x8*)(smem + ((wm * 64 + m * 16 + fr) << 7) + ko);
#pragma unroll
            for (int nn = 0; nn < 4; nn++)
                bv[nn] = *(const bf16x8*)(smem + 16384 + ((wn * 64 + nn * 16 + fr) << 7) + ko);
#pragma unroll
            for (int m = 0; m < 4; m++)
#pragma unroll
                for (int nn = 0; nn < 4; nn++)
                    acc[m][nn] = __builtin_amdgcn_mfma_f32_16x16x32_bf16(
                        af[m], bv[nn], acc[m][nn], 0, 0, 0);
        }
        __syncthreads();   // all reads of this tile done before restage
        if (t + 1 < NT) {
            const int off = (t + 1) << 7;   // 128 B per BK-tile within a row
#pragma unroll
            for (int j = 0; j < 4; j++) {
                gload_lds16(pa[j] + off, smem + j * 4096 + ldso);
                gload_lds16(pb[j] + off, smem + 16384 + j * 4096 + ldso);
            }
        }
    }

    if (MODE != 1) {
        // C/D layout (m89-verified): col = lane&15, row = (lane>>4)*4 + j
        float* C = (float*)Cv;
        const int crow0 = bm * 128 + wm * 64 + fq * 4;
        const int ccol0 = bn * 128 + wn * 64 + fr;
#pragma unroll
        for (int m = 0; m < 4; m++) {
#pragma unroll
            for (int nn = 0; nn < 4; nn++) {
                const int col = ccol0 + nn * 16;
                const float bv2 = (MODE == 2 && col >= 256) ? bias2[col - 256]
                                                            : bias[col];
#pragma unroll
                for (int j = 0; j < 4; j++) {
                    const int row = crow0 + m * 16 + j;
                    if (row < M) C[(size_t)row * N + col] = acc[m][nn][j] + bv2;
                }
            }
        }
    } else {
        // per-wave LDS transpose epilogue (R7-proven); last __syncthreads()
        // already guarantees all waves finished reading As/Bs.
        unsigned short* tile = (unsigned short*)smem + (size_t)w * (64 * 68);
        const int hh = bn * 2 + wn;                 // head, uniform per wave
        float bvs[4];
#pragma unroll
        for (int nn = 0; nn < 4; nn++) bvs[nn] = bias[hh * 64 + nn * 16 + fr];
#pragma unroll
        for (int m = 0; m < 4; m++)
#pragma unroll
            for (int nn = 0; nn < 4; nn++)
#pragma unroll
                for (int j = 0; j < 4; j++)
                    tile[(m * 16 + fq * 4 + j) * 68 + nn * 16 + fr] =
                        f2bf(acc[m][nn][j] + bvs[nn]);
        __syncthreads();
        unsigned short* VT = (unsigned short*)Cv;
        const int q4 = (lane & 15) * 4;
        const int prow = lane >> 4;                 // 0..3
#pragma unroll
        for (int it = 0; it < 16; ++it) {
            const int pl = it * 4 + prow;           // local pixel 0..63
            const int pixg = bm * 128 + wm * 64 + pl;
            if (pixg < M) {
                const int n = pixg / 11253;
                const int pix = pixg - n * 11253;
                bf16x4 v = *(const bf16x4*)&tile[pl * 68 + q4];
                *(bf16x4*)(VT + ((size_t)(n * 8 + hh) * 11253 + pix) * 64 + q4) = v;
            }
        }
    }
}

// ---------------------------------------------------------------------------
// Sampling (R6/R8-proven core): one wave per (n, q, h). XCD-pinned mapping:
// block b -> XCD b&7 (HW round-robin); each XCD owns 4 (n,h) slices walked
// sequentially in q -> ~1-2 hot slices (<=2.9 MB) per 4 MiB L2 at a time.
// Scalar softmax; lane-parallel bilinear metadata; shfl-broadcast gathers.
// off/logits read from the fused [4000 x 384] buffer.
// ---------------------------------------------------------------------------
__global__ __launch_bounds__(256)
void sample_k(const unsigned short* __restrict__ valueT, // [4][8][11253][64] bf16
              const float* __restrict__ refp,            // [4][1000][4][2]
              const float* __restrict__ fused,           // [4][1000][384]
              unsigned int* __restrict__ msout)          // [4][1000][256] dwords
{
    const int bid = blockIdx.x;          // 0..7999
    const int xcd = bid & 7;
    const int jj  = bid >> 3;            // 0..999
    const int sl  = jj / 250;            // 0..3
    const int qb  = jj - sl * 250;       // 0..249
    const int nh  = xcd * 4 + sl;        // 0..31 (= n*8 + h)
    const int q   = __builtin_amdgcn_readfirstlane(qb * 4 + (threadIdx.x >> 6));
    const int lane = threadIdx.x & 63;
    const int g    = lane >> 5;          // x-corner group (0: xb, 1: xb+1)
    const int n = nh >> 3, h = nh & 7;
    const int nq = n * 1000 + q;

    // softmax reduction over the 16 points (scalar, uniform loads)
    const float* lgp = fused + (size_t)nq * 384 + 256 + h * 16;
    float mx = lgp[0];
#pragma unroll
    for (int pp = 1; pp < 16; pp++) mx = fmaxf(mx, lgp[pp]);
    float s = 0.f;
#pragma unroll
    for (int pp = 0; pp < 16; pp++) s += __expf(lgp[pp] - mx);

    // per-point metadata on lane groups of 16 (lanes 0-31 are the sources)
    const int p  = lane & 15;
    const int lv = p >> 2;
    const int W  = lv == 0 ? 92 : lv == 1 ? 46 : lv == 2 ? 23 : 12;  // H == W
    const int st = lv == 0 ? 0 : lv == 1 ? 8464 : lv == 2 ? 10580 : 11109;

    const float a  = __expf(lgp[p] - mx) / s;
    const float rx = refp[(size_t)nq * 8 + lv * 2 + 0];
    const float ry = refp[(size_t)nq * 8 + lv * 2 + 1];
    const float ox = fused[(size_t)nq * 384 + h * 32 + p * 2 + 0];
    const float oy = fused[(size_t)nq * 384 + h * 32 + p * 2 + 1];

    const float x = rx * (float)W + ox - 0.5f;
    const float y = ry * (float)W + oy - 0.5f;
    const float xf = floorf(x), yf = floorf(y);
    const int x0 = (int)xf, y0 = (int)yf;
    const float lx = x - xf, ly = y - yf;
    const int xb = min(max(x0, 0), W - 2);
    const int yb = min(max(y0, 0), W - 2);
    const float wx0 = (xb     == x0) ? (1.f - lx) : ((xb     == x0 + 1) ? lx : 0.f);
    const float wx1 = (xb + 1 == x0) ? (1.f - lx) : ((xb + 1 == x0 + 1) ? lx : 0.f);
    const float wy0 = (yb     == y0) ? (1.f - ly) : ((yb     == y0 + 1) ? ly : 0.f);
    const float wy1 = (yb + 1 == y0) ? (1.f - ly) : ((yb + 1 == y0 + 1) ? ly : 0.f);
    const int idx0v = st + yb * W + xb;
    const int idx1v = idx0v + W;
    const float wxs = (lane & 16) ? wx1 : wx0;   // lane group picks its x-corner
    const float wav = a * wxs * wy0;
    const float wbv = a * wxs * wy1;

    const unsigned int* vb =
        (const unsigned int*)valueT + (size_t)nh * 11253 * 32;

    float acc0 = 0.f, acc1 = 0.f;
    const int srcb = g << 4;
#pragma unroll
    for (int pp = 0; pp < 16; pp++) {
        const int src = pp + srcb;           // lane pp (g=0) or pp+16 (g=1)
        const int   i0 = __shfl(idx0v, src);
        const int   i1 = __shfl(idx1v, src);
        const float w0 = __shfl(wav,   src);
        const float w1 = __shfl(wbv,   src);
        const unsigned d0 = vb[i0 * 32 + lane];   // lane>=32 reads pixel+1
        const unsigned d1 = vb[i1 * 32 + lane];
        acc0 = fmaf(w0, bflo(d0), acc0);
        acc1 = fmaf(w0, bfhi(d0), acc1);
        acc0 = fmaf(w1, bflo(d1), acc0);
        acc1 = fmaf(w1, bfhi(d1), acc1);
    }

    acc0 += __shfl(acc0, lane ^ 32);
    acc1 += __shfl(acc1, lane ^ 32);
    if (lane < 32) {
        const unsigned u = (unsigned)f2bf(acc0) | ((unsigned)f2bf(acc1) << 16);
        msout[(size_t)nq * 256 + h * 32 + (lane & 31)] = u;
    }
}

// ---------------------------------------------------------------------------
extern "C" void kernel_launch(void* const* d_in, const int* in_sizes, int n_in,
                              void* d_out, int out_size, void* d_ws, size_t ws_size,
                              hipStream_t stream) {
    (void)in_sizes; (void)n_in; (void)out_size; (void)ws_size;

    const float* query  = (const float*)d_in[0];
    const float* refp   = (const float*)d_in[1];
    const float* inpf   = (const float*)d_in[2];
    const float* W_off  = (const float*)d_in[5];
    const float* b_off  = (const float*)d_in[6];
    const float* W_attn = (const float*)d_in[7];
    const float* b_attn = (const float*)d_in[8];
    const float* W_val  = (const float*)d_in[9];
    const float* b_val  = (const float*)d_in[10];
    const float* W_out  = (const float*)d_in[11];
    const float* b_out  = (const float*)d_in[12];
    float* out = (float*)d_out;

    char* ws = (char*)d_ws;
    unsigned short* bf = (unsigned short*)ws;                    // 25,815,040 B
    unsigned short* inpfb   = bf;
    unsigned short* queryb  = bf + 11523072;
    unsigned short* W_offb  = bf + 12547072;   // [W_off;W_attn] = [384 x 256]
    unsigned short* W_valb  = bf + 12645376;
    unsigned short* W_outb  = bf + 12776448;
    unsigned short* valueT  = (unsigned short*)(ws + 25815040);  // 46,092,288 B
    float* fusedb = (float*)(ws + 71907328);                     //  6,144,000 B
    unsigned int* msoutu = (unsigned int*)(ws + 78051328);       //  4,096,000 B
    unsigned short* msoutb = (unsigned short*)msoutu;

    // 0. convert everything to bf16
    cvt_k<<<6303, 256, 0, stream>>>(inpf, query, W_off, W_attn, W_val, W_out, bf);
    // 1. value projection -> bf16 transposed [n][h][pix][64]
    gemm_bf16_tn<1><<<dim3(352, 4), 256, 0, stream>>>(
        inpfb, W_valb, b_val, nullptr, valueT, 45012, 512, 256);
    // 2. fused offsets+logits: [4000 x 384]
    gemm_bf16_tn<2><<<dim3(32, 3), 256, 0, stream>>>(
        queryb, W_offb, b_off, b_attn, fusedb, 4000, 384, 256);
    // 3. sampling (fused softmax), msout bf16
    sample_k<<<8000, 256, 0, stream>>>(valueT, refp, fusedb, msoutu);
    // 4. output projection
    gemm_bf16_tn<0><<<dim3(32, 2), 256, 0, stream>>>(
        msoutb, W_outb, b_out, nullptr, out, 4000, 256, 512);
}

// Round 10
// 95.915 us; speedup vs baseline: 2.0905x; 1.0546x over previous
//
#include <hip/hip_runtime.h>

// ---------------------------------------------------------------------------
// MS Deformable Attention (Deformable-DETR), MI355X gfx950.
//   0. cvt    : all f32 operands -> bf16 (one streaming kernel)
//   1. valueT = bf16( input_flatten @ W_val^T + b_val ) -> [n][h][pix][64]
//   2. fused  = query @ [W_off;W_attn]^T + [b_off;b_attn]  [4000 x 384] f32
//   3. msout  = bilinear-sample(valueT, loc, softmax(logits)) -> bf16
//   4. out    = msout @ W_out^T + b_out    [4000 x 256] f32
// vs R9: GEMM K-loop double-buffered (stage-at-top, one __syncthreads/iter)
// so global_load_lds latency hides under ds_read+MFMA. All else verbatim.
// ---------------------------------------------------------------------------

typedef __attribute__((ext_vector_type(4))) float f32x4;
typedef __attribute__((ext_vector_type(8))) short bf16x8;
typedef __attribute__((ext_vector_type(4))) short bf16x4;

static __device__ __forceinline__ unsigned short f2bf(float f) {
    unsigned u = __builtin_bit_cast(unsigned, f);
    u += 0x7FFFu + ((u >> 16) & 1u);   // round-to-nearest-even
    return (unsigned short)(u >> 16);
}
static __device__ __forceinline__ float bflo(unsigned d) {
    return __builtin_bit_cast(float, d << 16);
}
static __device__ __forceinline__ float bfhi(unsigned d) {
    return __builtin_bit_cast(float, d & 0xffff0000u);
}
static __device__ __forceinline__ void gload_lds16(const void* g, void* l) {
    __builtin_amdgcn_global_load_lds(
        (const __attribute__((address_space(1))) void*)g,
        (__attribute__((address_space(3))) void*)l, 16, 0, 0);
}

// ---------------------------------------------------------------------------
// f32 -> bf16 conversion of all operands into one packed buffer.
//   inpf 0 | query 11523072 | W_off 12547072 | W_attn 12612608
//   | W_val 12645376 | W_out 12776448 | total 12907520
// ---------------------------------------------------------------------------
__global__ __launch_bounds__(256)
void cvt_k(const float* __restrict__ s0, const float* __restrict__ s1,
           const float* __restrict__ s2, const float* __restrict__ s3,
           const float* __restrict__ s4, const float* __restrict__ s5,
           unsigned short* __restrict__ dst) {
    const size_t i8 = ((size_t)blockIdx.x * 256 + threadIdx.x) * 8;
    if (i8 >= 12907520u) return;
    const float* sp; size_t loc;
    if (i8 < 11523072u)      { sp = s0; loc = i8; }
    else if (i8 < 12547072u) { sp = s1; loc = i8 - 11523072u; }
    else if (i8 < 12612608u) { sp = s2; loc = i8 - 12547072u; }
    else if (i8 < 12645376u) { sp = s3; loc = i8 - 12612608u; }
    else if (i8 < 12776448u) { sp = s4; loc = i8 - 12645376u; }
    else                     { sp = s5; loc = i8 - 12776448u; }
    f32x4 a = *(const f32x4*)(sp + loc);
    f32x4 b = *(const f32x4*)(sp + loc + 4);
    bf16x8 r;
    r[0] = f2bf(a[0]); r[1] = f2bf(a[1]); r[2] = f2bf(a[2]); r[3] = f2bf(a[3]);
    r[4] = f2bf(b[0]); r[5] = f2bf(b[1]); r[6] = f2bf(b[2]); r[7] = f2bf(b[3]);
    *(bf16x8*)(dst + i8) = r;
}

// ---------------------------------------------------------------------------
// bf16 GEMM: C = A[M,K] @ B[N,K]^T + bias. BM=BN=128, BK=64, 4 waves 2x2.
// Double-buffered LDS (2 x {As 16KB, Bs 16KB}); per iter: issue next-tile
// global_load_lds FIRST, then ds_read+MFMA current, then one __syncthreads
// (drains vmcnt+lgkmcnt) -> stage latency hides under compute.
// Source col pre-XOR'd (b16 ^= row&7); read side XOR-matches.
// MODE 0: C f32 [M,N], bias[col].  MODE 2: dual bias (col>=256 -> bias2).
// MODE 1: C bf16 -> valueT[n][h][pix][64] via per-wave LDS-transpose epilogue.
// ---------------------------------------------------------------------------
template<int MODE>
__global__ __launch_bounds__(256)
void gemm_bf16_tn(const unsigned short* __restrict__ A,
                  const unsigned short* __restrict__ B,
                  const float* __restrict__ bias, const float* __restrict__ bias2,
                  void* __restrict__ Cv, int M, int N, int K) {
    __shared__ __align__(16) char smem[65536];   // 2 phases x (As+Bs)

    const int tid = threadIdx.x, lane = tid & 63, w = tid >> 6;
    const int wm = w >> 1, wn = w & 1;
    const int bm = blockIdx.x, bn = blockIdx.y;

    // staging map: LDS byte (j*4096 + w*1024 + lane*16) -> row j*32+w*8+(lane>>3),
    // 16B-block (lane&7). Source block pre-XOR'd by row&7 (= lane>>3 & 7).
    const int r8 = lane >> 3;
    const int colsrc = (((lane & 7) ^ r8) << 4);
    const char* pa[4]; const char* pb[4];
#pragma unroll
    for (int j = 0; j < 4; j++) {
        int ra = bm * 128 + j * 32 + w * 8 + r8; ra = ra < M ? ra : M - 1;
        int rb = bn * 128 + j * 32 + w * 8 + r8; rb = rb < N ? rb : N - 1;
        pa[j] = (const char*)A + (size_t)ra * ((size_t)K * 2) + colsrc;
        pb[j] = (const char*)B + (size_t)rb * ((size_t)K * 2) + colsrc;
    }
    const int ldso = w << 10;
    const int NT = K >> 6;

    f32x4 acc[4][4] = {};
    const int fr = lane & 15, fq = lane >> 4;
    const int k8b = fq << 4;            // fq*8 shorts = fq*16 bytes
    const int swzR = (fr & 7) << 4;     // read-side XOR (row&7 == fr&7)

    // prologue: stage tile 0 into phase 0
#pragma unroll
    for (int j = 0; j < 4; j++) {
        gload_lds16(pa[j], smem + j * 4096 + ldso);
        gload_lds16(pb[j], smem + 16384 + j * 4096 + ldso);
    }
    __syncthreads();   // tile 0 visible

    for (int t = 0; t < NT; ++t) {
        const int cur = (t & 1) << 15;
        // 1) issue next tile's stage into the other phase (async, overlaps MFMA)
        if (t + 1 < NT) {
            const int nxt = ((t + 1) & 1) << 15;
            const int off = (t + 1) << 7;   // 128 B per BK-tile within a row
#pragma unroll
            for (int j = 0; j < 4; j++) {
                gload_lds16(pa[j] + off, smem + nxt + j * 4096 + ldso);
                gload_lds16(pb[j] + off, smem + nxt + 16384 + j * 4096 + ldso);
            }
        }
        // 2) compute current tile
#pragma unroll
        for (int kk = 0; kk < 2; ++kk) {
            const int ko = ((kk << 6) + k8b) ^ swzR;
            bf16x8 af[4], bv[4];
#pragma unroll
            for (int m = 0; m < 4; m++)
                af[m] = *(const bf16x8*)(smem + cur + ((wm * 64 + m * 16 + fr) << 7) + ko);
#pragma unroll
            for (int nn = 0; nn < 4; nn++)
                bv[nn] = *(const bf16x8*)(smem + cur + 16384 + ((wn * 64 + nn * 16 + fr) << 7) + ko);
#pragma unroll
            for (int m = 0; m < 4; m++)
#pragma unroll
                for (int nn = 0; nn < 4; nn++)
                    acc[m][nn] = __builtin_amdgcn_mfma_f32_16x16x32_bf16(
                        af[m], bv[nn], acc[m][nn], 0, 0, 0);
        }
        // 3) one barrier: drains this iter's stage (overlapped) + retires reads
        __syncthreads();
    }

    if (MODE != 1) {
        // C/D layout (m89-verified): col = lane&15, row = (lane>>4)*4 + j
        float* C = (float*)Cv;
        const int crow0 = bm * 128 + wm * 64 + fq * 4;
        const int ccol0 = bn * 128 + wn * 64 + fr;
#pragma unroll
        for (int m = 0; m < 4; m++) {
#pragma unroll
            for (int nn = 0; nn < 4; nn++) {
                const int col = ccol0 + nn * 16;
                const float bv2 = (MODE == 2 && col >= 256) ? bias2[col - 256]
                                                            : bias[col];
#pragma unroll
                for (int j = 0; j < 4; j++) {
                    const int row = crow0 + m * 16 + j;
                    if (row < M) C[(size_t)row * N + col] = acc[m][nn][j] + bv2;
                }
            }
        }
    } else {
        // per-wave LDS transpose epilogue (R7-proven); the final K-loop
        // __syncthreads guarantees all waves are done with smem.
        unsigned short* tile = (unsigned short*)smem + (size_t)w * (64 * 68);
        const int hh = bn * 2 + wn;                 // head, uniform per wave
        float bvs[4];
#pragma unroll
        for (int nn = 0; nn < 4; nn++) bvs[nn] = bias[hh * 64 + nn * 16 + fr];
#pragma unroll
        for (int m = 0; m < 4; m++)
#pragma unroll
            for (int nn = 0; nn < 4; nn++)
#pragma unroll
                for (int j = 0; j < 4; j++)
                    tile[(m * 16 + fq * 4 + j) * 68 + nn * 16 + fr] =
                        f2bf(acc[m][nn][j] + bvs[nn]);
        __syncthreads();
        unsigned short* VT = (unsigned short*)Cv;
        const int q4 = (lane & 15) * 4;
        const int prow = lane >> 4;                 // 0..3
#pragma unroll
        for (int it = 0; it < 16; ++it) {
            const int pl = it * 4 + prow;           // local pixel 0..63
            const int pixg = bm * 128 + wm * 64 + pl;
            if (pixg < M) {
                const int n = pixg / 11253;
                const int pix = pixg - n * 11253;
                bf16x4 v = *(const bf16x4*)&tile[pl * 68 + q4];
                *(bf16x4*)(VT + ((size_t)(n * 8 + hh) * 11253 + pix) * 64 + q4) = v;
            }
        }
    }
}

// ---------------------------------------------------------------------------
// Sampling (R9-proven): one wave per (n, q, h). XCD-pinned slice mapping;
// scalar softmax; lane-parallel bilinear metadata; shfl-broadcast gathers.
// ---------------------------------------------------------------------------
__global__ __launch_bounds__(256)
void sample_k(const unsigned short* __restrict__ valueT, // [4][8][11253][64] bf16
              const float* __restrict__ refp,            // [4][1000][4][2]
              const float* __restrict__ fused,           // [4][1000][384]
              unsigned int* __restrict__ msout)          // [4][1000][256] dwords
{
    const int bid = blockIdx.x;          // 0..7999
    const int xcd = bid & 7;
    const int jj  = bid >> 3;            // 0..999
    const int sl  = jj / 250;            // 0..3
    const int qb  = jj - sl * 250;       // 0..249
    const int nh  = xcd * 4 + sl;        // 0..31 (= n*8 + h)
    const int q   = __builtin_amdgcn_readfirstlane(qb * 4 + (threadIdx.x >> 6));
    const int lane = threadIdx.x & 63;
    const int g    = lane >> 5;          // x-corner group (0: xb, 1: xb+1)
    const int n = nh >> 3, h = nh & 7;
    const int nq = n * 1000 + q;

    // softmax reduction over the 16 points (scalar, uniform loads)
    const float* lgp = fused + (size_t)nq * 384 + 256 + h * 16;
    float mx = lgp[0];
#pragma unroll
    for (int pp = 1; pp < 16; pp++) mx = fmaxf(mx, lgp[pp]);
    float s = 0.f;
#pragma unroll
    for (int pp = 0; pp < 16; pp++) s += __expf(lgp[pp] - mx);

    // per-point metadata on lane groups of 16 (lanes 0-31 are the sources)
    const int p  = lane & 15;
    const int lv = p >> 2;
    const int W  = lv == 0 ? 92 : lv == 1 ? 46 : lv == 2 ? 23 : 12;  // H == W
    const int st = lv == 0 ? 0 : lv == 1 ? 8464 : lv == 2 ? 10580 : 11109;

    const float a  = __expf(lgp[p] - mx) / s;
    const float rx = refp[(size_t)nq * 8 + lv * 2 + 0];
    const float ry = refp[(size_t)nq * 8 + lv * 2 + 1];
    const float ox = fused[(size_t)nq * 384 + h * 32 + p * 2 + 0];
    const float oy = fused[(size_t)nq * 384 + h * 32 + p * 2 + 1];

    const float x = rx * (float)W + ox - 0.5f;
    const float y = ry * (float)W + oy - 0.5f;
    const float xf = floorf(x), yf = floorf(y);
    const int x0 = (int)xf, y0 = (int)yf;
    const float lx = x - xf, ly = y - yf;
    const int xb = min(max(x0, 0), W - 2);
    const int yb = min(max(y0, 0), W - 2);
    const float wx0 = (xb     == x0) ? (1.f - lx) : ((xb     == x0 + 1) ? lx : 0.f);
    const float wx1 = (xb + 1 == x0) ? (1.f - lx) : ((xb + 1 == x0 + 1) ? lx : 0.f);
    const float wy0 = (yb     == y0) ? (1.f - ly) : ((yb     == y0 + 1) ? ly : 0.f);
    const float wy1 = (yb + 1 == y0) ? (1.f - ly) : ((yb + 1 == y0 + 1) ? ly : 0.f);
    const int idx0v = st + yb * W + xb;
    const int idx1v = idx0v + W;
    const float wxs = (lane & 16) ? wx1 : wx0;   // lane group picks its x-corner
    const float wav = a * wxs * wy0;
    const float wbv = a * wxs * wy1;

    const unsigned int* vb =
        (const unsigned int*)valueT + (size_t)nh * 11253 * 32;

    float acc0 = 0.f, acc1 = 0.f;
    const int srcb = g << 4;
#pragma unroll
    for (int pp = 0; pp < 16; pp++) {
        const int src = pp + srcb;           // lane pp (g=0) or pp+16 (g=1)
        const int   i0 = __shfl(idx0v, src);
        const int   i1 = __shfl(idx1v, src);
        const float w0 = __shfl(wav,   src);
        const float w1 = __shfl(wbv,   src);
        const unsigned d0 = vb[i0 * 32 + lane];   // lane>=32 reads pixel+1
        const unsigned d1 = vb[i1 * 32 + lane];
        acc0 = fmaf(w0, bflo(d0), acc0);
        acc1 = fmaf(w0, bfhi(d0), acc1);
        acc0 = fmaf(w1, bflo(d1), acc0);
        acc1 = fmaf(w1, bfhi(d1), acc1);
    }

    acc0 += __shfl(acc0, lane ^ 32);
    acc1 += __shfl(acc1, lane ^ 32);
    if (lane < 32) {
        const unsigned u = (unsigned)f2bf(acc0) | ((unsigned)f2bf(acc1) << 16);
        msout[(size_t)nq * 256 + h * 32 + (lane & 31)] = u;
    }
}

// ---------------------------------------------------------------------------
extern "C" void kernel_launch(void* const* d_in, const int* in_sizes, int n_in,
                              void* d_out, int out_size, void* d_ws, size_t ws_size,
                              hipStream_t stream) {
    (void)in_sizes; (void)n_in; (void)out_size; (void)ws_size;

    const float* query  = (const float*)d_in[0];
    const float* refp   = (const float*)d_in[1];
    const float* inpf   = (const float*)d_in[2];
    const float* W_off  = (const float*)d_in[5];
    const float* b_off  = (const float*)d_in[6];
    const float* W_attn = (const float*)d_in[7];
    const float* b_attn = (const float*)d_in[8];
    const float* W_val  = (const float*)d_in[9];
    const float* b_val  = (const float*)d_in[10];
    const float* W_out  = (const float*)d_in[11];
    const float* b_out  = (const float*)d_in[12];
    float* out = (float*)d_out;

    char* ws = (char*)d_ws;
    unsigned short* bf = (unsigned short*)ws;                    // 25,815,040 B
    unsigned short* inpfb   = bf;
    unsigned short* queryb  = bf + 11523072;
    unsigned short* W_offb  = bf + 12547072;   // [W_off;W_attn] = [384 x 256]
    unsigned short* W_valb  = bf + 12645376;
    unsigned short* W_outb  = bf + 12776448;
    unsigned short* valueT  = (unsigned short*)(ws + 25815040);  // 46,092,288 B
    float* fusedb = (float*)(ws + 71907328);                     //  6,144,000 B
    unsigned int* msoutu = (unsigned int*)(ws + 78051328);       //  4,096,000 B
    unsigned short* msoutb = (unsigned short*)msoutu;

    // 0. convert everything to bf16
    cvt_k<<<6303, 256, 0, stream>>>(inpf, query, W_off, W_attn, W_val, W_out, bf);
    // 1. value projection -> bf16 transposed [n][h][pix][64]
    gemm_bf16_tn<1><<<dim3(352, 4), 256, 0, stream>>>(
        inpfb, W_valb, b_val, nullptr, valueT, 45012, 512, 256);
    // 2. fused offsets+logits: [4000 x 384]
    gemm_bf16_tn<2><<<dim3(32, 3), 256, 0, stream>>>(
        queryb, W_offb, b_off, b_attn, fusedb, 4000, 384, 256);
    // 3. sampling (fused softmax), msout bf16
    sample_k<<<8000, 256, 0, stream>>>(valueT, refp, fusedb, msoutu);
    // 4. output projection
    gemm_bf16_tn<0><<<dim3(32, 2), 256, 0, stream>>>(
        msoutb, W_outb, b_out, nullptr, out, 4000, 256, 512);
}